// Round 5
// baseline (3069.915 us; speedup 1.0000x reference)
//
#include <hip/hip_runtime.h>

// ---------------------------------------------------------------------------
// Corr_upsample_resize_norm: 6-level correlation pyramid.
// INPUT ORDER (setup_inputs dict order): x0, xp0, x1, xp1, ..., x5, xp5,
// motion_state  ->  x_i = d_in[2i], xp_i = d_in[2i+1].  All float32.
// OUTPUT: float32 (reference output dtype), out_size = 10,948,122 elements:
//   [dw0, corr0, dw1, corr1, ..., dw5, corr5]
// Level i: S=96>>i, s=2^i. corr is 96x96 always, but distinct dot products
// are only B*S*S*D*D (D = 9,5,3,3,3,3) between LOW-RES feature vectors.
// Scratch (inside dw0 element region [0, 1492992), written only at the end):
//   float lc1[115200] @ elem 0, lc2[10368], lc3[2592], lc4[648], lc5[162]
//     (scratch ends at element 128970)
//   uint  slots[6] @ elements [1492986, 1492992) (last 24 B of dw0)
// k_norm(0) writes t < 1492986; k_norm0_tail fixes the 6 slot-aliased
// elements after all slot readers are done.
// ---------------------------------------------------------------------------

__global__ __launch_bounds__(64) void k_init(unsigned int* slots) {
  if (threadIdx.x < 6) slots[threadIdx.x] = 0u;  // 0.0f; true max is >= 0
}

// Level 0: full-resolution correlation (s=1). corr0 == dw0 (pre-norm).
// grid (3 xtile, 12 ytile, b*9+dy), block 256 = 32x * 8y. 9 dx accumulators.
__global__ __launch_bounds__(256) void k_corr0(
    const float* __restrict__ f1, const float* __restrict__ f2,
    float* __restrict__ corr_out, unsigned int* __restrict__ maxslot) {
  const int x = blockIdx.x * 32 + (threadIdx.x & 31);
  const int y = blockIdx.y * 8 + (threadIdx.x >> 5);
  const int b = blockIdx.z / 9;
  const int dyi = blockIdx.z % 9;
  const int hy = y + dyi - 4;
  float acc[9];
#pragma unroll
  for (int i = 0; i < 9; ++i) acc[i] = 0.f;
  if (hy >= 0 && hy < 96) {
    const float* p1 = f1 + (size_t)b * 512 * 9216 + y * 96 + x;
    const float* p2 = f2 + (size_t)b * 512 * 9216 + hy * 96 + x;
    bool ok[9];
#pragma unroll
    for (int dx = 0; dx < 9; ++dx) {
      int xx = x + dx - 4;
      ok[dx] = (xx >= 0 && xx < 96);
    }
    for (int c = 0; c < 512; ++c) {
      float a = p1[(size_t)c * 9216];
      const float* r2 = p2 + (size_t)c * 9216;
#pragma unroll
      for (int dx = 0; dx < 9; ++dx)
        if (ok[dx]) acc[dx] = fmaf(a, r2[dx - 4], acc[dx]);
    }
  }
  float mx = 0.f;
  float* o = corr_out + ((size_t)b * 81 + dyi * 9) * 9216 + y * 96 + x;
#pragma unroll
  for (int dx = 0; dx < 9; ++dx) {
    float v = acc[dx];
    v = v >= 0.f ? v : 0.01f * v;
    o[(size_t)dx * 9216] = v;
    mx = fmaxf(mx, v);
  }
#pragma unroll
  for (int off = 32; off; off >>= 1) mx = fmaxf(mx, __shfl_down(mx, off));
  if ((threadIdx.x & 63) == 0) atomicMax((int*)maxslot, __float_as_int(mx));
}

// Level 1 low-res correlation, C=1024, S=48, offsets [-2,2]^2 (25).
// grid (3,6, b*5+dy), block 128 = 16x * 8y. 5 dx accumulators, full C loop.
// lc1 layout: [b][Y][X][dy][dx] (25 per pixel), float.
__global__ __launch_bounds__(128) void k_lc1(
    const float* __restrict__ f1, const float* __restrict__ f2,
    float* __restrict__ lc1) {
  const int X = blockIdx.x * 16 + (threadIdx.x & 15);
  const int Y = blockIdx.y * 8 + (threadIdx.x >> 4);
  const int b = blockIdx.z / 5;
  const int dyi = blockIdx.z % 5;
  const int YY = Y + dyi - 2;
  float acc[5];
#pragma unroll
  for (int i = 0; i < 5; ++i) acc[i] = 0.f;
  if (YY >= 0 && YY < 48) {
    const float* p1 = f1 + (size_t)b * 1024 * 2304 + Y * 48 + X;
    const float* p2 = f2 + (size_t)b * 1024 * 2304 + YY * 48 + X;
    bool ok[5];
#pragma unroll
    for (int dx = 0; dx < 5; ++dx) {
      int xx = X + dx - 2;
      ok[dx] = (xx >= 0 && xx < 48);
    }
    for (int c = 0; c < 1024; ++c) {
      float a = p1[(size_t)c * 2304];
      const float* r2 = p2 + (size_t)c * 2304;
#pragma unroll
      for (int dx = 0; dx < 5; ++dx)
        if (ok[dx]) acc[dx] = fmaf(a, r2[dx - 2], acc[dx]);
    }
  }
  float* op = lc1 + ((size_t)(b * 48 + Y) * 48 + X) * 25 + dyi * 5;
#pragma unroll
  for (int dx = 0; dx < 5; ++dx) op[dx] = acc[dx];
}

// Levels 2..5 low-res correlation, offsets [-1,1]^2 (9). Thread = (pixel, o).
// lc layout: [p][9], float.
__global__ __launch_bounds__(64) void k_lc_small(
    const float* __restrict__ f1, const float* __restrict__ f2,
    float* __restrict__ lc, const int S, const int C) {
  const int SS = S * S;
  const int p = blockIdx.x * 64 + threadIdx.x;
  if (p >= 2 * SS) return;
  const int o = blockIdx.y;
  const int oy = o / 3 - 1, ox = o % 3 - 1;
  const int b = p / SS, r = p % SS, Y = r / S, X = r % S;
  float v = 0.f;
  const int YY = Y + oy, XX = X + ox;
  if (YY >= 0 && YY < S && XX >= 0 && XX < S) {
    const float* p1 = f1 + (size_t)b * C * SS + r;
    const float* p2 = f2 + (size_t)b * C * SS + YY * S + XX;
    for (int c = 0; c < C; ++c)
      v = fmaf(p1[(size_t)c * SS], p2[(size_t)c * SS], v);
  }
  lc[(size_t)p * 9 + o] = v;
}

// Expansion for levels 1..5: LC -> corr (leaky) + dw (unnormalized) + max.
__global__ __launch_bounds__(256) void k_expand(
    const float* __restrict__ lc, float* __restrict__ out_corr,
    float* __restrict__ out_dw, unsigned int* __restrict__ maxslot,
    const int lvl, const int R) {
  const int t = blockIdx.x * 256 + threadIdx.x;
  float contrib = 0.f;
  if (t < 1492992) {
    const int x = t % 96;
    const int y = (t / 96) % 96;
    const int d = (t / 9216) % 81;
    const int b = t / 746496;
    const int hy = y + d / 9 - 4;
    const int hx = x + d % 9 - 4;
    float val = 0.f;
    if (hy >= 0 && hy < 96 && hx >= 0 && hx < 96) {
      const int S = 96 >> lvl;
      const int Y1 = y >> lvl, X1 = x >> lvl;
      const int oy = (hy >> lvl) - Y1 + R;
      const int ox = (hx >> lvl) - X1 + R;
      const int DD = 2 * R + 1;
      val = lc[(((size_t)(b * S + Y1) * S + X1) * DD + oy) * DD + ox];
      val = val >= 0.f ? val : 0.01f * val;
    }
    out_corr[t] = val;
    const int m = (1 << lvl) - 1;
    if (((y | x) & m) == 0) {
      const int S = 96 >> lvl;
      out_dw[((size_t)(b * 81 + d) * S + (y >> lvl)) * S + (x >> lvl)] = val;
      contrib = val;  // max is over dw (decimated) values only
    }
  }
#pragma unroll
  for (int off = 32; off; off >>= 1)
    contrib = fmaxf(contrib, __shfl_down(contrib, off));
  if ((threadIdx.x & 63) == 0) atomicMax((int*)maxslot, __float_as_int(contrib));
}

// Normalize: out[dwoff+t] = out[srcoff+t] / max  (float32).
__global__ __launch_bounds__(256) void k_norm(
    float* __restrict__ out, const unsigned int* __restrict__ slots,
    const int lvl, const size_t dwoff, const size_t srcoff, const int n) {
  const int t = blockIdx.x * 256 + threadIdx.x;
  if (t >= n) return;
  const float m = __int_as_float((int)slots[lvl]);
  out[dwoff + t] = out[srcoff + t] / m;
}

// Last 6 dw0 elements alias the slot bytes: read slot0 first, then write.
// Single wave: the m-load precedes the stores in the instruction stream.
__global__ __launch_bounds__(64) void k_norm0_tail(
    float* __restrict__ out, const unsigned int* __restrict__ slots) {
  const float m = __int_as_float((int)slots[0]);
  if (threadIdx.x < 6) {
    const int t = 1492986 + threadIdx.x;
    out[t] = out[1492992 + t] / m;
  }
}

extern "C" void kernel_launch(void* const* d_in, const int* in_sizes, int n_in,
                              void* d_out, int out_size, void* d_ws,
                              size_t ws_size, hipStream_t stream) {
  // setup_inputs() dict order: x0, xp0, x1, xp1, ..., x5, xp5, motion_state.
  const float* x[6];
  const float* xp[6];
  for (int i = 0; i < 6; ++i) {
    x[i] = (const float*)d_in[2 * i];
    xp[i] = (const float*)d_in[2 * i + 1];
  }
  float* out = (float*)d_out;

  // Scratch inside dw0 element region [0, 1492992):
  float* lc1 = out;            // 115200 floats
  float* lc2 = lc1 + 115200;   // 10368
  float* lc3 = lc2 + 10368;    // 2592
  float* lc4 = lc3 + 2592;     // 648
  float* lc5 = lc4 + 648;      // 162   (scratch ends at element 128970)
  unsigned int* slots = (unsigned int*)(out + 1492986);  // last 24 B of dw0

  static const size_t dwoff[6] = {0,       2985984, 4852224,
                                  6438528, 7954848, 9453672};
  static const size_t croff[6] = {1492992, 3359232, 4945536,
                                  6461856, 7960680, 9455130};
  float* lcs[6] = {nullptr, lc1, lc2, lc3, lc4, lc5};
  const int Cs[6] = {512, 1024, 512, 256, 256, 256};

  k_init<<<dim3(1), dim3(64), 0, stream>>>(slots);
  k_corr0<<<dim3(3, 12, 18), dim3(256), 0, stream>>>(x[0], xp[0],
                                                     out + croff[0], slots);
  k_lc1<<<dim3(3, 6, 10), dim3(128), 0, stream>>>(x[1], xp[1], lc1);
  for (int l = 2; l <= 5; ++l) {
    int S = 96 >> l;
    int NP = 2 * S * S;
    k_lc_small<<<dim3((NP + 63) / 64, 9), dim3(64), 0, stream>>>(
        x[l], xp[l], lcs[l], S, Cs[l]);
  }
  for (int l = 1; l <= 5; ++l) {
    int R = (l == 1) ? 2 : 1;
    k_expand<<<dim3(5832), dim3(256), 0, stream>>>(
        lcs[l], out + croff[l], out + dwoff[l], slots + l, l, R);
  }
  // Levels 1..5 normalize dw in place (readers of slots[1..5]).
  for (int l = 1; l <= 5; ++l) {
    int S = 96 >> l;
    int n = 162 * S * S;
    k_norm<<<dim3((n + 255) / 256), dim3(256), 0, stream>>>(
        out, slots, l, dwoff[l], dwoff[l], n);
  }
  // Level 0 last: overwrites the lc/slot scratch region. Main part skips the
  // 6 elements aliasing the slots; the tail kernel fixes them up.
  k_norm<<<dim3((1492986 + 255) / 256), dim3(256), 0, stream>>>(
      out, slots, 0, dwoff[0], croff[0], 1492986);
  k_norm0_tail<<<dim3(1), dim3(64), 0, stream>>>(out, slots);
}

// Round 6
// 2068.808 us; speedup vs baseline: 1.4839x; 1.4839x over previous
//
#include <hip/hip_runtime.h>

// ---------------------------------------------------------------------------
// Corr_upsample_resize_norm: 6-level correlation pyramid.
// INPUT ORDER (setup_inputs dict order): x0, xp0, x1, xp1, ..., x5, xp5,
// motion_state  ->  x_i = d_in[2i], xp_i = d_in[2i+1].  All float32.
// OUTPUT: float32, out_size = 10,948,122 elements:
//   [dw0, corr0, dw1, corr1, ..., dw5, corr5]
// Scratch (all inside d_out, in regions not yet finalized):
//   float lc1[115200] @ dw0 elem 0; lc2[10368], lc3[2592], lc4[648], lc5[162]
//     (ends at elem 128970 << 1492992)
//   float part1[921600] @ corr1 region (croff[1]=3359232; overwritten later
//     by k_expand(1), which runs after k_red1 consumed it)
//   uint  slots[6] @ dw0 elems [1492986,1492992) (last 24 B of dw0)
// k_norm(0) writes t < 1492986; k_norm0_tail fixes the 6 slot-aliased elems.
// ---------------------------------------------------------------------------

__global__ __launch_bounds__(64) void k_init(unsigned int* slots) {
  if (threadIdx.x < 6) slots[threadIdx.x] = 0u;  // 0.0f; true max is >= 0
}

// Level 0: full-resolution correlation (s=1). corr0 == dw0 (pre-norm).
// grid (3 xtile, 12 ytile, b*9+dy), block 256 = 32x * 8y. 9 dx accumulators.
__global__ __launch_bounds__(256) void k_corr0(
    const float* __restrict__ f1, const float* __restrict__ f2,
    float* __restrict__ corr_out, unsigned int* __restrict__ maxslot) {
  const int x = blockIdx.x * 32 + (threadIdx.x & 31);
  const int y = blockIdx.y * 8 + (threadIdx.x >> 5);
  const int b = blockIdx.z / 9;
  const int dyi = blockIdx.z % 9;
  const int hy = y + dyi - 4;
  float acc[9];
#pragma unroll
  for (int i = 0; i < 9; ++i) acc[i] = 0.f;
  if (hy >= 0 && hy < 96) {
    const float* p1 = f1 + (size_t)b * 512 * 9216 + y * 96 + x;
    const float* p2 = f2 + (size_t)b * 512 * 9216 + hy * 96 + x;
    bool ok[9];
#pragma unroll
    for (int dx = 0; dx < 9; ++dx) {
      int xx = x + dx - 4;
      ok[dx] = (xx >= 0 && xx < 96);
    }
    for (int c = 0; c < 512; ++c) {
      float a = p1[(size_t)c * 9216];
      const float* r2 = p2 + (size_t)c * 9216;
#pragma unroll
      for (int dx = 0; dx < 9; ++dx)
        if (ok[dx]) acc[dx] = fmaf(a, r2[dx - 4], acc[dx]);
    }
  }
  float mx = 0.f;
  float* o = corr_out + ((size_t)b * 81 + dyi * 9) * 9216 + y * 96 + x;
#pragma unroll
  for (int dx = 0; dx < 9; ++dx) {
    float v = acc[dx];
    v = v >= 0.f ? v : 0.01f * v;
    o[(size_t)dx * 9216] = v;
    mx = fmaxf(mx, v);
  }
#pragma unroll
  for (int off = 32; off; off >>= 1) mx = fmaxf(mx, __shfl_down(mx, off));
  if ((threadIdx.x & 63) == 0) atomicMax((int*)maxslot, __float_as_int(mx));
}

// Level 1 low-res correlation partials. One WAVE per (Y row, channel group,
// batch): grid (48, 8, 2), block 64 (lane = X, 48 active).
// Per c: 6 coalesced row loads + 4 shuffles (shift f1) + 25 FMA; all edge
// masks hoisted out of the c-loop. acc2[dy][dx] on lane L accumulates
// f1[L-dx+2] * f2[Y+dy-2, L]; the final cross-lane pull regroups to
// out[X][dy][dx] = f1[X] * f2[Y+dy-2, X+dx-2].
// part layout: [gc][b][o=dy*5+dx][Y][X] (coalesced stores).
__global__ __launch_bounds__(64) void k_lc1p(
    const float* __restrict__ f1, const float* __restrict__ f2,
    float* __restrict__ part) {
  const int X = threadIdx.x;          // 0..63, active < 48
  const int Y = blockIdx.x;           // 0..47
  const int gc = blockIdx.y;          // 0..7  -> channels [gc*128, gc*128+128)
  const int b = blockIdx.z;           // 0..1
  const bool xin = (X < 48);

  float acc2[5][5];
#pragma unroll
  for (int i = 0; i < 5; ++i)
#pragma unroll
    for (int j = 0; j < 5; ++j) acc2[i][j] = 0.f;

  bool okdy[5];
#pragma unroll
  for (int dy = 0; dy < 5; ++dy) {
    int YY = Y + dy - 2;
    okdy[dy] = (YY >= 0 && YY < 48);
  }
  const float* p1 = f1 + (size_t)b * 1024 * 2304 + Y * 48;
  const float* p2 = f2 + (size_t)b * 1024 * 2304;

  const int c0 = gc * 128;
  for (int c = c0; c < c0 + 128; ++c) {
    float a = xin ? p1[(size_t)c * 2304 + X] : 0.f;
    float as[5];
#pragma unroll
    for (int dx = 0; dx < 5; ++dx) {
      int src = X - dx + 2;
      src = src < 0 ? 0 : (src > 63 ? 63 : src);
      as[dx] = (dx == 2) ? a : __shfl(a, src);
    }
#pragma unroll
    for (int dy = 0; dy < 5; ++dy) {
      int YY = Y + dy - 2;
      float v = (okdy[dy] && xin) ? p2[(size_t)c * 2304 + YY * 48 + X] : 0.f;
#pragma unroll
      for (int dx = 0; dx < 5; ++dx) acc2[dy][dx] = fmaf(as[dx], v, acc2[dy][dx]);
    }
  }

  // Regroup + mask + store (coalesced per (dy,dx) plane).
  float* pb = part + ((size_t)(gc * 2 + b) * 25) * 2304 + Y * 48;
#pragma unroll
  for (int dy = 0; dy < 5; ++dy)
#pragma unroll
    for (int dx = 0; dx < 5; ++dx) {
      int src = X + dx - 2;
      int scl = src < 0 ? 0 : (src > 63 ? 63 : src);
      float val = __shfl(acc2[dy][dx], scl);
      bool okx = (X + dx - 2 >= 0) && (X + dx - 2 < 48);
      if (xin) pb[(size_t)(dy * 5 + dx) * 2304 + X] = (okdy[dy] && okx) ? val : 0.f;
    }
}

// Sum the 8 channel-group partials into lc1 ([b][Y][X][25] layout).
__global__ __launch_bounds__(256) void k_red1(const float* __restrict__ part,
                                              float* __restrict__ lc1) {
  const int t = blockIdx.x * 256 + threadIdx.x;
  if (t >= 115200) return;
  const int o = t / 4608;    // 0..24
  const int pix = t % 4608;  // b*2304 + Y*48 + X
  const int b = pix / 2304, r = pix % 2304;
  float s = 0.f;
#pragma unroll
  for (int g = 0; g < 8; ++g)
    s += part[((size_t)(g * 2 + b) * 25 + o) * 2304 + r];
  lc1[(size_t)pix * 25 + o] = s;
}

// Levels 2..5: one WAVE per (pixel, offset); lanes split channels, butterfly
// reduce. grid (2*S*S, 9), block 64. lc layout: [p][9].
__global__ __launch_bounds__(64) void k_lc_ow(
    const float* __restrict__ f1, const float* __restrict__ f2,
    float* __restrict__ lc, const int S, const int C) {
  const int SS = S * S;
  const int p = blockIdx.x;
  const int o = blockIdx.y;
  const int oy = o / 3 - 1, ox = o % 3 - 1;
  const int b = p / SS, r = p % SS, Y = r / S, X = r % S;
  const int YY = Y + oy, XX = X + ox;
  float v = 0.f;
  if (YY >= 0 && YY < S && XX >= 0 && XX < S) {
    const float* p1 = f1 + (size_t)b * C * SS + r;
    const float* p2 = f2 + (size_t)b * C * SS + YY * S + XX;
    for (int c = threadIdx.x; c < C; c += 64)
      v = fmaf(p1[(size_t)c * SS], p2[(size_t)c * SS], v);
  }
#pragma unroll
  for (int off = 32; off; off >>= 1) v += __shfl_down(v, off);
  if (threadIdx.x == 0) lc[(size_t)p * 9 + o] = v;
}

// Expansion for levels 1..5: LC -> corr (leaky) + dw (unnormalized) + max.
__global__ __launch_bounds__(256) void k_expand(
    const float* __restrict__ lc, float* __restrict__ out_corr,
    float* __restrict__ out_dw, unsigned int* __restrict__ maxslot,
    const int lvl, const int R) {
  const int t = blockIdx.x * 256 + threadIdx.x;
  float contrib = 0.f;
  if (t < 1492992) {
    const int x = t % 96;
    const int y = (t / 96) % 96;
    const int d = (t / 9216) % 81;
    const int b = t / 746496;
    const int hy = y + d / 9 - 4;
    const int hx = x + d % 9 - 4;
    float val = 0.f;
    if (hy >= 0 && hy < 96 && hx >= 0 && hx < 96) {
      const int S = 96 >> lvl;
      const int Y1 = y >> lvl, X1 = x >> lvl;
      const int oy = (hy >> lvl) - Y1 + R;
      const int ox = (hx >> lvl) - X1 + R;
      const int DD = 2 * R + 1;
      val = lc[(((size_t)(b * S + Y1) * S + X1) * DD + oy) * DD + ox];
      val = val >= 0.f ? val : 0.01f * val;
    }
    out_corr[t] = val;
    const int m = (1 << lvl) - 1;
    if (((y | x) & m) == 0) {
      const int S = 96 >> lvl;
      out_dw[((size_t)(b * 81 + d) * S + (y >> lvl)) * S + (x >> lvl)] = val;
      contrib = val;  // max is over dw (decimated) values only
    }
  }
#pragma unroll
  for (int off = 32; off; off >>= 1)
    contrib = fmaxf(contrib, __shfl_down(contrib, off));
  if ((threadIdx.x & 63) == 0) atomicMax((int*)maxslot, __float_as_int(contrib));
}

// Normalize: out[dwoff+t] = out[srcoff+t] / max  (float32).
__global__ __launch_bounds__(256) void k_norm(
    float* __restrict__ out, const unsigned int* __restrict__ slots,
    const int lvl, const size_t dwoff, const size_t srcoff, const int n) {
  const int t = blockIdx.x * 256 + threadIdx.x;
  if (t >= n) return;
  const float m = __int_as_float((int)slots[lvl]);
  out[dwoff + t] = out[srcoff + t] / m;
}

// Last 6 dw0 elements alias the slot bytes: read slot0 first, then write.
__global__ __launch_bounds__(64) void k_norm0_tail(
    float* __restrict__ out, const unsigned int* __restrict__ slots) {
  const float m = __int_as_float((int)slots[0]);
  if (threadIdx.x < 6) {
    const int t = 1492986 + threadIdx.x;
    out[t] = out[1492992 + t] / m;
  }
}

extern "C" void kernel_launch(void* const* d_in, const int* in_sizes, int n_in,
                              void* d_out, int out_size, void* d_ws,
                              size_t ws_size, hipStream_t stream) {
  // setup_inputs() dict order: x0, xp0, x1, xp1, ..., x5, xp5, motion_state.
  const float* x[6];
  const float* xp[6];
  for (int i = 0; i < 6; ++i) {
    x[i] = (const float*)d_in[2 * i];
    xp[i] = (const float*)d_in[2 * i + 1];
  }
  float* out = (float*)d_out;

  static const size_t dwoff[6] = {0,       2985984, 4852224,
                                  6438528, 7954848, 9453672};
  static const size_t croff[6] = {1492992, 3359232, 4945536,
                                  6461856, 7960680, 9455130};

  // Scratch inside dw0 element region [0, 1492992):
  float* lc1 = out;            // 115200 floats
  float* lc2 = lc1 + 115200;   // 10368
  float* lc3 = lc2 + 10368;    // 2592
  float* lc4 = lc3 + 2592;     // 648
  float* lc5 = lc4 + 648;      // 162   (scratch ends at element 128970)
  unsigned int* slots = (unsigned int*)(out + 1492986);  // last 24 B of dw0
  // part1 (921600 floats) in the corr1 region, consumed before k_expand(1).
  float* part1 = out + croff[1];

  float* lcs[6] = {nullptr, lc1, lc2, lc3, lc4, lc5};
  const int Cs[6] = {512, 1024, 512, 256, 256, 256};

  k_init<<<dim3(1), dim3(64), 0, stream>>>(slots);
  k_corr0<<<dim3(3, 12, 18), dim3(256), 0, stream>>>(x[0], xp[0],
                                                     out + croff[0], slots);
  k_lc1p<<<dim3(48, 8, 2), dim3(64), 0, stream>>>(x[1], xp[1], part1);
  k_red1<<<dim3((115200 + 255) / 256), dim3(256), 0, stream>>>(part1, lc1);
  for (int l = 2; l <= 5; ++l) {
    int S = 96 >> l;
    k_lc_ow<<<dim3(2 * S * S, 9), dim3(64), 0, stream>>>(x[l], xp[l], lcs[l],
                                                         S, Cs[l]);
  }
  for (int l = 1; l <= 5; ++l) {
    int R = (l == 1) ? 2 : 1;
    k_expand<<<dim3(5832), dim3(256), 0, stream>>>(
        lcs[l], out + croff[l], out + dwoff[l], slots + l, l, R);
  }
  // Levels 1..5 normalize dw in place (readers of slots[1..5]).
  for (int l = 1; l <= 5; ++l) {
    int S = 96 >> l;
    int n = 162 * S * S;
    k_norm<<<dim3((n + 255) / 256), dim3(256), 0, stream>>>(
        out, slots, l, dwoff[l], dwoff[l], n);
  }
  // Level 0 last: overwrites the lc/slot scratch region. Main part skips the
  // 6 elements aliasing the slots; the tail kernel fixes them up.
  k_norm<<<dim3((1492986 + 255) / 256), dim3(256), 0, stream>>>(
      out, slots, 0, dwoff[0], croff[0], 1492986);
  k_norm0_tail<<<dim3(1), dim3(64), 0, stream>>>(out, slots);
}

// Round 7
// 1897.684 us; speedup vs baseline: 1.6177x; 1.0902x over previous
//
#include <hip/hip_runtime.h>

// ---------------------------------------------------------------------------
// Corr_upsample_resize_norm: 6-level correlation pyramid.
// INPUT ORDER (setup_inputs dict order): x0, xp0, x1, xp1, ..., x5, xp5,
// motion_state  ->  x_i = d_in[2i], xp_i = d_in[2i+1].  All float32.
// OUTPUT: float32, out_size = 10,948,122 elements:
//   [dw0, corr0, dw1, corr1, ..., dw5, corr5]
// Scratch map (all inside d_out, consumed before the region is finalized):
//   dw0 region [0, 1492992):
//     lc1[115200]@0, lc2[10368]@115200, lc3[2592]@125568, lc4[648]@128160,
//     lc5[162]@128808; lcrow partials: P2[82944]@200000, P3[20736]@300000,
//     P4[5184]@330000, P5[1296]@340000;  uint slots[6] @ elem 1492986.
//   corr0 partials part0[5971968] @ 2985984 (level1..4 regions; consumed by
//     k_corr0red before k_lc1p/k_expand reuse that space).
//   part1[921600] @ croff[1]=3359232 (consumed by k_red1 before k_expand(1)).
// ---------------------------------------------------------------------------

__global__ __launch_bounds__(64) void k_init(unsigned int* slots) {
  if (threadIdx.x < 6) slots[threadIdx.x] = 0u;  // 0.0f; true max is >= 0
}

// Level 0 partials. Wave-per-row, channel-group split G=4.
// grid (96, 4, 2), block 128 (lane = x, 96 active).
// acc[dy][dxi] on lane x accumulates f1[y, x+4-dxi] * f2[y+dy-4, x];
// k_corr0red regroups x-coordinates. part0 layout: [g][b][y][dy][dxi][x96].
__global__ __launch_bounds__(128) void k_corr0p(
    const float* __restrict__ f1, const float* __restrict__ f2,
    float* __restrict__ part) {
  const int x = threadIdx.x;   // 0..127, active < 96
  const int y = blockIdx.x;    // 0..95
  const int gc = blockIdx.y;   // 0..3 -> channels [gc*128, gc*128+128)
  const int b = blockIdx.z;    // 0..1
  const bool xin = (x < 96);

  float acc[9][9];
#pragma unroll
  for (int i = 0; i < 9; ++i)
#pragma unroll
    for (int j = 0; j < 9; ++j) acc[i][j] = 0.f;

  bool okdx[9], okdy[9];
  int off1[9], off2[9];
#pragma unroll
  for (int i = 0; i < 9; ++i) {
    int xs = x + 4 - i;
    okdx[i] = xin && (xs >= 0) && (xs < 96);
    off1[i] = y * 96 + (xs < 0 ? 0 : (xs > 95 ? 95 : xs));
    int yy = y + i - 4;
    okdy[i] = xin && (yy >= 0) && (yy < 96);
    off2[i] = (yy < 0 ? 0 : (yy > 95 ? 95 : yy)) * 96 + (xin ? x : 0);
  }

  const float* f1b = f1 + (size_t)b * 512 * 9216;
  const float* f2b = f2 + (size_t)b * 512 * 9216;
  const int c0 = gc * 128;
  for (int c = c0; c < c0 + 128; ++c) {
    const float* p = f1b + (size_t)c * 9216;
    const float* q = f2b + (size_t)c * 9216;
    float as[9], v[9];
#pragma unroll
    for (int i = 0; i < 9; ++i) as[i] = okdx[i] ? p[off1[i]] : 0.f;
#pragma unroll
    for (int i = 0; i < 9; ++i) v[i] = okdy[i] ? q[off2[i]] : 0.f;
#pragma unroll
    for (int dy = 0; dy < 9; ++dy)
#pragma unroll
      for (int dxi = 0; dxi < 9; ++dxi)
        acc[dy][dxi] = fmaf(as[dxi], v[dy], acc[dy][dxi]);
  }

  if (xin) {
    size_t base = (((size_t)(gc * 2 + b) * 96 + y) * 81) * 96 + x;
#pragma unroll
    for (int dy = 0; dy < 9; ++dy)
#pragma unroll
      for (int dxi = 0; dxi < 9; ++dxi)
        part[base + (size_t)(dy * 9 + dxi) * 96] = acc[dy][dxi];
  }
}

// Reduce 4 channel groups, regroup x, leaky, store corr0, track max (slot0).
__global__ __launch_bounds__(256) void k_corr0red(
    const float* __restrict__ part, float* __restrict__ corr0,
    unsigned int* __restrict__ maxslot) {
  const int t = blockIdx.x * 256 + threadIdx.x;  // < 1492992 exact
  const int x = t % 96;
  const int y = (t / 96) % 96;
  const int d = (t / 9216) % 81;
  const int b = t / 746496;
  const int dy = d / 9, dx = d % 9;
  const int xs = x + dx - 4;  // lane coordinate in partial space
  float v = 0.f;
  if (xs >= 0 && xs < 96) {
    size_t base = ((((size_t)b * 96 + y) * 9 + dy) * 9 + dx) * 96 + xs;
    v = part[base] + part[base + 1492992] + part[base + 2 * 1492992] +
        part[base + 3 * 1492992];
  }
  v = v >= 0.f ? v : 0.01f * v;
  corr0[t] = v;
  float mx = v;
#pragma unroll
  for (int off = 32; off; off >>= 1) mx = fmaxf(mx, __shfl_down(mx, off));
  if ((threadIdx.x & 63) == 0) atomicMax((int*)maxslot, __float_as_int(mx));
}

// Level 1 low-res correlation partials (unchanged from round 6).
// One WAVE per (Y row, channel group, batch): grid (48, 8, 2), block 64.
__global__ __launch_bounds__(64) void k_lc1p(
    const float* __restrict__ f1, const float* __restrict__ f2,
    float* __restrict__ part) {
  const int X = threadIdx.x;          // 0..63, active < 48
  const int Y = blockIdx.x;           // 0..47
  const int gc = blockIdx.y;          // 0..7
  const int b = blockIdx.z;           // 0..1
  const bool xin = (X < 48);

  float acc2[5][5];
#pragma unroll
  for (int i = 0; i < 5; ++i)
#pragma unroll
    for (int j = 0; j < 5; ++j) acc2[i][j] = 0.f;

  bool okdy[5];
#pragma unroll
  for (int dy = 0; dy < 5; ++dy) {
    int YY = Y + dy - 2;
    okdy[dy] = (YY >= 0 && YY < 48);
  }
  const float* p1 = f1 + (size_t)b * 1024 * 2304 + Y * 48;
  const float* p2 = f2 + (size_t)b * 1024 * 2304;

  const int c0 = gc * 128;
  for (int c = c0; c < c0 + 128; ++c) {
    float a = xin ? p1[(size_t)c * 2304 + X] : 0.f;
    float as[5];
#pragma unroll
    for (int dx = 0; dx < 5; ++dx) {
      int src = X - dx + 2;
      src = src < 0 ? 0 : (src > 63 ? 63 : src);
      as[dx] = (dx == 2) ? a : __shfl(a, src);
    }
#pragma unroll
    for (int dy = 0; dy < 5; ++dy) {
      int YY = Y + dy - 2;
      float v = (okdy[dy] && xin) ? p2[(size_t)c * 2304 + YY * 48 + X] : 0.f;
#pragma unroll
      for (int dx = 0; dx < 5; ++dx) acc2[dy][dx] = fmaf(as[dx], v, acc2[dy][dx]);
    }
  }

  float* pb = part + ((size_t)(gc * 2 + b) * 25) * 2304 + Y * 48;
#pragma unroll
  for (int dy = 0; dy < 5; ++dy)
#pragma unroll
    for (int dx = 0; dx < 5; ++dx) {
      int src = X + dx - 2;
      int scl = src < 0 ? 0 : (src > 63 ? 63 : src);
      float val = __shfl(acc2[dy][dx], scl);
      bool okx = (X + dx - 2 >= 0) && (X + dx - 2 < 48);
      if (xin) pb[(size_t)(dy * 5 + dx) * 2304 + X] = (okdy[dy] && okx) ? val : 0.f;
    }
}

// Sum the 8 channel-group partials into lc1 ([b][Y][X][25] layout).
__global__ __launch_bounds__(256) void k_red1(const float* __restrict__ part,
                                              float* __restrict__ lc1) {
  const int t = blockIdx.x * 256 + threadIdx.x;
  if (t >= 115200) return;
  const int o = t / 4608;    // 0..24
  const int pix = t % 4608;  // b*2304 + Y*48 + X
  const int b = pix / 2304, r = pix % 2304;
  float s = 0.f;
#pragma unroll
  for (int g = 0; g < 8; ++g)
    s += part[((size_t)(g * 2 + b) * 25 + o) * 2304 + r];
  lc1[(size_t)pix * 25 + o] = s;
}

// Levels 2..5 partials: lanes over SPATIAL positions (RW rows per wave),
// channel-split G=8. grid (ceil(S/RW), 8, 2), block 64.
// acc[dy][dxi] on lane (y,X): f1[y, X+1-dxi] * f2[y+dy-1, X].
// part layout: [g][b][y][dy][dxi][X].
__global__ __launch_bounds__(64) void k_lcrow(
    const float* __restrict__ f1, const float* __restrict__ f2,
    float* __restrict__ part, const int S, const int C, const int cpg,
    const int RW) {
  const int lane = threadIdx.x;
  const int SS = S * S;
  const int yr = lane / S;
  const int X = lane % S;
  const int y = blockIdx.x * RW + yr;
  const int gc = blockIdx.y;
  const int b = blockIdx.z;
  const bool act = (yr < RW) && (y < S);

  float acc[3][3];
#pragma unroll
  for (int i = 0; i < 3; ++i)
#pragma unroll
    for (int j = 0; j < 3; ++j) acc[i][j] = 0.f;

  bool okdx[3], okdy[3];
  int off1[3], off2[3];
#pragma unroll
  for (int i = 0; i < 3; ++i) {
    int xs = X + 1 - i;
    okdx[i] = act && (xs >= 0) && (xs < S);
    off1[i] = (act ? y : 0) * S + (xs < 0 ? 0 : (xs >= S ? S - 1 : xs));
    int yy = y + i - 1;
    okdy[i] = act && (yy >= 0) && (yy < S);
    off2[i] = (yy < 0 ? 0 : (yy >= S ? S - 1 : yy)) * S + X;
  }

  const float* f1b = f1 + (size_t)b * C * SS;
  const float* f2b = f2 + (size_t)b * C * SS;
  const int c0 = gc * cpg;
  for (int c = c0; c < c0 + cpg; ++c) {
    const float* p = f1b + (size_t)c * SS;
    const float* q = f2b + (size_t)c * SS;
    float as[3], v[3];
#pragma unroll
    for (int i = 0; i < 3; ++i) as[i] = okdx[i] ? p[off1[i]] : 0.f;
#pragma unroll
    for (int i = 0; i < 3; ++i) v[i] = okdy[i] ? q[off2[i]] : 0.f;
#pragma unroll
    for (int dy = 0; dy < 3; ++dy)
#pragma unroll
      for (int dxi = 0; dxi < 3; ++dxi)
        acc[dy][dxi] = fmaf(as[dxi], v[dy], acc[dy][dxi]);
  }

  if (act) {
    size_t base = ((size_t)(gc * 2 + b) * S + y) * 9 * S + X;
#pragma unroll
    for (int dy = 0; dy < 3; ++dy)
#pragma unroll
      for (int dxi = 0; dxi < 3; ++dxi)
        part[base + (size_t)(dy * 3 + dxi) * S] = acc[dy][dxi];
  }
}

// Reduce G=8 groups + x-regroup into lc[p][9] for levels 2..5.
__global__ __launch_bounds__(256) void k_lcred(const float* __restrict__ part,
                                               float* __restrict__ lc,
                                               const int S) {
  const int SS = S * S;
  const int t = blockIdx.x * 256 + threadIdx.x;
  if (t >= 2 * SS * 9) return;
  const int o = t % 9;
  const int p = t / 9;
  const int b = p / SS, r = p % SS, y = r / S, X = r % S;
  const int dy = o / 3, dx = o % 3;
  const int xs = X + dx - 1;
  float v = 0.f;
  if (xs >= 0 && xs < S) {
    size_t base = ((size_t)b * S + y) * 9 * S + (size_t)(dy * 3 + dx) * S + xs;
    const size_t gstride = (size_t)2 * S * 9 * S;
#pragma unroll
    for (int g = 0; g < 8; ++g) v += part[base + g * gstride];
  }
  lc[(size_t)p * 9 + o] = v;
}

// Expansion for levels 1..5: LC -> corr (leaky) + dw (unnormalized) + max.
__global__ __launch_bounds__(256) void k_expand(
    const float* __restrict__ lc, float* __restrict__ out_corr,
    float* __restrict__ out_dw, unsigned int* __restrict__ maxslot,
    const int lvl, const int R) {
  const int t = blockIdx.x * 256 + threadIdx.x;
  float contrib = 0.f;
  if (t < 1492992) {
    const int x = t % 96;
    const int y = (t / 96) % 96;
    const int d = (t / 9216) % 81;
    const int b = t / 746496;
    const int hy = y + d / 9 - 4;
    const int hx = x + d % 9 - 4;
    float val = 0.f;
    if (hy >= 0 && hy < 96 && hx >= 0 && hx < 96) {
      const int S = 96 >> lvl;
      const int Y1 = y >> lvl, X1 = x >> lvl;
      const int oy = (hy >> lvl) - Y1 + R;
      const int ox = (hx >> lvl) - X1 + R;
      const int DD = 2 * R + 1;
      val = lc[(((size_t)(b * S + Y1) * S + X1) * DD + oy) * DD + ox];
      val = val >= 0.f ? val : 0.01f * val;
    }
    out_corr[t] = val;
    const int m = (1 << lvl) - 1;
    if (((y | x) & m) == 0) {
      const int S = 96 >> lvl;
      out_dw[((size_t)(b * 81 + d) * S + (y >> lvl)) * S + (x >> lvl)] = val;
      contrib = val;
    }
  }
#pragma unroll
  for (int off = 32; off; off >>= 1)
    contrib = fmaxf(contrib, __shfl_down(contrib, off));
  if ((threadIdx.x & 63) == 0) atomicMax((int*)maxslot, __float_as_int(contrib));
}

// Normalize: out[dwoff+t] = out[srcoff+t] / max  (float32).
__global__ __launch_bounds__(256) void k_norm(
    float* __restrict__ out, const unsigned int* __restrict__ slots,
    const int lvl, const size_t dwoff, const size_t srcoff, const int n) {
  const int t = blockIdx.x * 256 + threadIdx.x;
  if (t >= n) return;
  const float m = __int_as_float((int)slots[lvl]);
  out[dwoff + t] = out[srcoff + t] / m;
}

// Last 6 dw0 elements alias the slot bytes: read slot0 first, then write.
__global__ __launch_bounds__(64) void k_norm0_tail(
    float* __restrict__ out, const unsigned int* __restrict__ slots) {
  const float m = __int_as_float((int)slots[0]);
  if (threadIdx.x < 6) {
    const int t = 1492986 + threadIdx.x;
    out[t] = out[1492992 + t] / m;
  }
}

extern "C" void kernel_launch(void* const* d_in, const int* in_sizes, int n_in,
                              void* d_out, int out_size, void* d_ws,
                              size_t ws_size, hipStream_t stream) {
  const float* x[6];
  const float* xp[6];
  for (int i = 0; i < 6; ++i) {
    x[i] = (const float*)d_in[2 * i];
    xp[i] = (const float*)d_in[2 * i + 1];
  }
  float* out = (float*)d_out;

  static const size_t dwoff[6] = {0,       2985984, 4852224,
                                  6438528, 7954848, 9453672};
  static const size_t croff[6] = {1492992, 3359232, 4945536,
                                  6461856, 7960680, 9455130};

  // Scratch inside dw0 element region [0, 1492992):
  float* lc1 = out;            // 115200
  float* lc2 = lc1 + 115200;   // 10368
  float* lc3 = lc2 + 10368;    // 2592
  float* lc4 = lc3 + 2592;     // 648
  float* lc5 = lc4 + 648;      // 162  (ends 128970)
  float* P2 = out + 200000;    // 82944
  float* P3 = out + 300000;    // 20736
  float* P4 = out + 330000;    // 5184
  float* P5 = out + 340000;    // 1296 (ends 341296)
  unsigned int* slots = (unsigned int*)(out + 1492986);
  // corr0 partials (5971968 floats) in level1..4 regions; consumed before
  // k_lc1p / k_expand reuse that space.
  float* part0 = out + 2985984;
  // part1 (921600 floats) in corr1 region, consumed before k_expand(1).
  float* part1 = out + croff[1];

  float* lcs[6] = {nullptr, lc1, lc2, lc3, lc4, lc5};
  float* Ps[6] = {nullptr, nullptr, P2, P3, P4, P5};
  const int Cs[6] = {512, 1024, 512, 256, 256, 256};

  k_init<<<dim3(1), dim3(64), 0, stream>>>(slots);
  k_corr0p<<<dim3(96, 4, 2), dim3(128), 0, stream>>>(x[0], xp[0], part0);
  k_corr0red<<<dim3(5832), dim3(256), 0, stream>>>(part0, out + croff[0],
                                                   slots);
  k_lc1p<<<dim3(48, 8, 2), dim3(64), 0, stream>>>(x[1], xp[1], part1);
  k_red1<<<dim3((115200 + 255) / 256), dim3(256), 0, stream>>>(part1, lc1);
  for (int l = 2; l <= 5; ++l) {
    int S = 96 >> l;
    int RW = 64 / S;
    int cpg = Cs[l] / 8;
    k_lcrow<<<dim3((S + RW - 1) / RW, 8, 2), dim3(64), 0, stream>>>(
        x[l], xp[l], Ps[l], S, Cs[l], cpg, RW);
  }
  for (int l = 2; l <= 5; ++l) {
    int S = 96 >> l;
    int n = 2 * S * S * 9;
    k_lcred<<<dim3((n + 255) / 256), dim3(256), 0, stream>>>(Ps[l], lcs[l], S);
  }
  for (int l = 1; l <= 5; ++l) {
    int R = (l == 1) ? 2 : 1;
    k_expand<<<dim3(5832), dim3(256), 0, stream>>>(
        lcs[l], out + croff[l], out + dwoff[l], slots + l, l, R);
  }
  for (int l = 1; l <= 5; ++l) {
    int S = 96 >> l;
    int n = 162 * S * S;
    k_norm<<<dim3((n + 255) / 256), dim3(256), 0, stream>>>(
        out, slots, l, dwoff[l], dwoff[l], n);
  }
  k_norm<<<dim3((1492986 + 255) / 256), dim3(256), 0, stream>>>(
      out, slots, 0, dwoff[0], croff[0], 1492986);
  k_norm0_tail<<<dim3(1), dim3(64), 0, stream>>>(out, slots);
}

// Round 8
// 329.742 us; speedup vs baseline: 9.3100x; 5.7551x over previous
//
#include <hip/hip_runtime.h>

// ---------------------------------------------------------------------------
// Corr_upsample_resize_norm: 6-level correlation pyramid.
// INPUT ORDER (setup_inputs dict order): x0, xp0, x1, xp1, ..., x5, xp5,
// motion_state  ->  x_i = d_in[2i], xp_i = d_in[2i+1].  All float32.
// OUTPUT: float32, out_size = 10,948,122 elements:
//   [dw0, corr0, dw1, corr1, ..., dw5, corr5]
// Scratch map (all inside d_out, consumed before the region is finalized):
//   dw0 region [0, 1492992):
//     lc1[115200]@0, lc2[10368]@115200, lc3[2592]@125568, lc4[648]@128160,
//     lc5[162]@128808; lcrow partials: P2[82944]@200000, P3[20736]@300000,
//     P4[5184]@330000, P5[1296]@340000;
//     maxbuf[6*5832]@400000 (per-block maxima; NO global atomics — reduced
//     by k_finmax into slots);  uint slots[6] @ elem 1492986.
//   corr0 partials part0[5971968] @ 2985984 (level1..4 regions; consumed by
//     k_corr0red before k_lc1p/k_expand reuse that space).
//   part1[921600] @ croff[1]=3359232 (consumed by k_red1 before k_expand(1)).
// ---------------------------------------------------------------------------

// Level 0 partials. Wave-per-row, channel-group split G=4.
// grid (96, 4, 2), block 128 (lane = x, 96 active).
// acc[dy][dxi] on lane x accumulates f1[y, x+4-dxi] * f2[y+dy-4, x];
// k_corr0red regroups x-coordinates. part0 layout: [g][b][y][dy][dxi][x96].
__global__ __launch_bounds__(128) void k_corr0p(
    const float* __restrict__ f1, const float* __restrict__ f2,
    float* __restrict__ part) {
  const int x = threadIdx.x;   // 0..127, active < 96
  const int y = blockIdx.x;    // 0..95
  const int gc = blockIdx.y;   // 0..3 -> channels [gc*128, gc*128+128)
  const int b = blockIdx.z;    // 0..1
  const bool xin = (x < 96);

  float acc[9][9];
#pragma unroll
  for (int i = 0; i < 9; ++i)
#pragma unroll
    for (int j = 0; j < 9; ++j) acc[i][j] = 0.f;

  bool okdx[9], okdy[9];
  int off1[9], off2[9];
#pragma unroll
  for (int i = 0; i < 9; ++i) {
    int xs = x + 4 - i;
    okdx[i] = xin && (xs >= 0) && (xs < 96);
    off1[i] = y * 96 + (xs < 0 ? 0 : (xs > 95 ? 95 : xs));
    int yy = y + i - 4;
    okdy[i] = xin && (yy >= 0) && (yy < 96);
    off2[i] = (yy < 0 ? 0 : (yy > 95 ? 95 : yy)) * 96 + (xin ? x : 0);
  }

  const float* f1b = f1 + (size_t)b * 512 * 9216;
  const float* f2b = f2 + (size_t)b * 512 * 9216;
  const int c0 = gc * 128;
  for (int c = c0; c < c0 + 128; ++c) {
    const float* p = f1b + (size_t)c * 9216;
    const float* q = f2b + (size_t)c * 9216;
    float as[9], v[9];
#pragma unroll
    for (int i = 0; i < 9; ++i) as[i] = okdx[i] ? p[off1[i]] : 0.f;
#pragma unroll
    for (int i = 0; i < 9; ++i) v[i] = okdy[i] ? q[off2[i]] : 0.f;
#pragma unroll
    for (int dy = 0; dy < 9; ++dy)
#pragma unroll
      for (int dxi = 0; dxi < 9; ++dxi)
        acc[dy][dxi] = fmaf(as[dxi], v[dy], acc[dy][dxi]);
  }

  if (xin) {
    size_t base = (((size_t)(gc * 2 + b) * 96 + y) * 81) * 96 + x;
#pragma unroll
    for (int dy = 0; dy < 9; ++dy)
#pragma unroll
      for (int dxi = 0; dxi < 9; ++dxi)
        part[base + (size_t)(dy * 9 + dxi) * 96] = acc[dy][dxi];
  }
}

// Reduce 4 channel groups, regroup x, leaky, store corr0.
// Block max -> plain store to maxbuf[blockIdx] (no atomics).
__global__ __launch_bounds__(256) void k_corr0red(
    const float* __restrict__ part, float* __restrict__ corr0,
    float* __restrict__ maxbuf) {
  const int t = blockIdx.x * 256 + threadIdx.x;  // < 1492992 exact
  const int x = t % 96;
  const int y = (t / 96) % 96;
  const int d = (t / 9216) % 81;
  const int b = t / 746496;
  const int dy = d / 9, dx = d % 9;
  const int xs = x + dx - 4;  // lane coordinate in partial space
  float v = 0.f;
  if (xs >= 0 && xs < 96) {
    size_t base = ((((size_t)b * 96 + y) * 9 + dy) * 9 + dx) * 96 + xs;
    v = part[base] + part[base + 1492992] + part[base + 2 * 1492992] +
        part[base + 3 * 1492992];
  }
  v = v >= 0.f ? v : 0.01f * v;
  corr0[t] = v;
  float mx = v;
#pragma unroll
  for (int off = 32; off; off >>= 1) mx = fmaxf(mx, __shfl_down(mx, off));
  __shared__ float wm[4];
  if ((threadIdx.x & 63) == 0) wm[threadIdx.x >> 6] = mx;
  __syncthreads();
  if (threadIdx.x == 0)
    maxbuf[blockIdx.x] =
        fmaxf(fmaxf(wm[0], wm[1]), fmaxf(wm[2], wm[3]));
}

// Level 1 low-res correlation partials.
// One WAVE per (Y row, channel group, batch): grid (48, 8, 2), block 64.
__global__ __launch_bounds__(64) void k_lc1p(
    const float* __restrict__ f1, const float* __restrict__ f2,
    float* __restrict__ part) {
  const int X = threadIdx.x;          // 0..63, active < 48
  const int Y = blockIdx.x;           // 0..47
  const int gc = blockIdx.y;          // 0..7
  const int b = blockIdx.z;           // 0..1
  const bool xin = (X < 48);

  float acc2[5][5];
#pragma unroll
  for (int i = 0; i < 5; ++i)
#pragma unroll
    for (int j = 0; j < 5; ++j) acc2[i][j] = 0.f;

  bool okdy[5];
#pragma unroll
  for (int dy = 0; dy < 5; ++dy) {
    int YY = Y + dy - 2;
    okdy[dy] = (YY >= 0 && YY < 48);
  }
  const float* p1 = f1 + (size_t)b * 1024 * 2304 + Y * 48;
  const float* p2 = f2 + (size_t)b * 1024 * 2304;

  const int c0 = gc * 128;
  for (int c = c0; c < c0 + 128; ++c) {
    float a = xin ? p1[(size_t)c * 2304 + X] : 0.f;
    float as[5];
#pragma unroll
    for (int dx = 0; dx < 5; ++dx) {
      int src = X - dx + 2;
      src = src < 0 ? 0 : (src > 63 ? 63 : src);
      as[dx] = (dx == 2) ? a : __shfl(a, src);
    }
#pragma unroll
    for (int dy = 0; dy < 5; ++dy) {
      int YY = Y + dy - 2;
      float v = (okdy[dy] && xin) ? p2[(size_t)c * 2304 + YY * 48 + X] : 0.f;
#pragma unroll
      for (int dx = 0; dx < 5; ++dx) acc2[dy][dx] = fmaf(as[dx], v, acc2[dy][dx]);
    }
  }

  float* pb = part + ((size_t)(gc * 2 + b) * 25) * 2304 + Y * 48;
#pragma unroll
  for (int dy = 0; dy < 5; ++dy)
#pragma unroll
    for (int dx = 0; dx < 5; ++dx) {
      int src = X + dx - 2;
      int scl = src < 0 ? 0 : (src > 63 ? 63 : src);
      float val = __shfl(acc2[dy][dx], scl);
      bool okx = (X + dx - 2 >= 0) && (X + dx - 2 < 48);
      if (xin) pb[(size_t)(dy * 5 + dx) * 2304 + X] = (okdy[dy] && okx) ? val : 0.f;
    }
}

// Sum the 8 channel-group partials into lc1 ([b][Y][X][25] layout).
__global__ __launch_bounds__(256) void k_red1(const float* __restrict__ part,
                                              float* __restrict__ lc1) {
  const int t = blockIdx.x * 256 + threadIdx.x;
  if (t >= 115200) return;
  const int o = t / 4608;    // 0..24
  const int pix = t % 4608;  // b*2304 + Y*48 + X
  const int b = pix / 2304, r = pix % 2304;
  float s = 0.f;
#pragma unroll
  for (int g = 0; g < 8; ++g)
    s += part[((size_t)(g * 2 + b) * 25 + o) * 2304 + r];
  lc1[(size_t)pix * 25 + o] = s;
}

// Levels 2..5 partials: lanes over SPATIAL positions (RW rows per wave),
// channel-split G=8. grid (ceil(S/RW), 8, 2), block 64.
__global__ __launch_bounds__(64) void k_lcrow(
    const float* __restrict__ f1, const float* __restrict__ f2,
    float* __restrict__ part, const int S, const int C, const int cpg,
    const int RW) {
  const int lane = threadIdx.x;
  const int SS = S * S;
  const int yr = lane / S;
  const int X = lane % S;
  const int y = blockIdx.x * RW + yr;
  const int gc = blockIdx.y;
  const int b = blockIdx.z;
  const bool act = (yr < RW) && (y < S);

  float acc[3][3];
#pragma unroll
  for (int i = 0; i < 3; ++i)
#pragma unroll
    for (int j = 0; j < 3; ++j) acc[i][j] = 0.f;

  bool okdx[3], okdy[3];
  int off1[3], off2[3];
#pragma unroll
  for (int i = 0; i < 3; ++i) {
    int xs = X + 1 - i;
    okdx[i] = act && (xs >= 0) && (xs < S);
    off1[i] = (act ? y : 0) * S + (xs < 0 ? 0 : (xs >= S ? S - 1 : xs));
    int yy = y + i - 1;
    okdy[i] = act && (yy >= 0) && (yy < S);
    off2[i] = (yy < 0 ? 0 : (yy >= S ? S - 1 : yy)) * S + X;
  }

  const float* f1b = f1 + (size_t)b * C * SS;
  const float* f2b = f2 + (size_t)b * C * SS;
  const int c0 = gc * cpg;
  for (int c = c0; c < c0 + cpg; ++c) {
    const float* p = f1b + (size_t)c * SS;
    const float* q = f2b + (size_t)c * SS;
    float as[3], v[3];
#pragma unroll
    for (int i = 0; i < 3; ++i) as[i] = okdx[i] ? p[off1[i]] : 0.f;
#pragma unroll
    for (int i = 0; i < 3; ++i) v[i] = okdy[i] ? q[off2[i]] : 0.f;
#pragma unroll
    for (int dy = 0; dy < 3; ++dy)
#pragma unroll
      for (int dxi = 0; dxi < 3; ++dxi)
        acc[dy][dxi] = fmaf(as[dxi], v[dy], acc[dy][dxi]);
  }

  if (act) {
    size_t base = ((size_t)(gc * 2 + b) * S + y) * 9 * S + X;
#pragma unroll
    for (int dy = 0; dy < 3; ++dy)
#pragma unroll
      for (int dxi = 0; dxi < 3; ++dxi)
        part[base + (size_t)(dy * 3 + dxi) * S] = acc[dy][dxi];
  }
}

// Reduce G=8 groups + x-regroup into lc[p][9] for levels 2..5.
__global__ __launch_bounds__(256) void k_lcred(const float* __restrict__ part,
                                               float* __restrict__ lc,
                                               const int S) {
  const int SS = S * S;
  const int t = blockIdx.x * 256 + threadIdx.x;
  if (t >= 2 * SS * 9) return;
  const int o = t % 9;
  const int p = t / 9;
  const int b = p / SS, r = p % SS, y = r / S, X = r % S;
  const int dy = o / 3, dx = o % 3;
  const int xs = X + dx - 1;
  float v = 0.f;
  if (xs >= 0 && xs < S) {
    size_t base = ((size_t)b * S + y) * 9 * S + (size_t)(dy * 3 + dx) * S + xs;
    const size_t gstride = (size_t)2 * S * 9 * S;
#pragma unroll
    for (int g = 0; g < 8; ++g) v += part[base + g * gstride];
  }
  lc[(size_t)p * 9 + o] = v;
}

// Expansion for levels 1..5: LC -> corr (leaky) + dw (unnormalized).
// Block max -> plain store to maxbuf[blockIdx] (no atomics).
__global__ __launch_bounds__(256) void k_expand(
    const float* __restrict__ lc, float* __restrict__ out_corr,
    float* __restrict__ out_dw, float* __restrict__ maxbuf,
    const int lvl, const int R) {
  const int t = blockIdx.x * 256 + threadIdx.x;
  float contrib = 0.f;
  if (t < 1492992) {
    const int x = t % 96;
    const int y = (t / 96) % 96;
    const int d = (t / 9216) % 81;
    const int b = t / 746496;
    const int hy = y + d / 9 - 4;
    const int hx = x + d % 9 - 4;
    float val = 0.f;
    if (hy >= 0 && hy < 96 && hx >= 0 && hx < 96) {
      const int S = 96 >> lvl;
      const int Y1 = y >> lvl, X1 = x >> lvl;
      const int oy = (hy >> lvl) - Y1 + R;
      const int ox = (hx >> lvl) - X1 + R;
      const int DD = 2 * R + 1;
      val = lc[(((size_t)(b * S + Y1) * S + X1) * DD + oy) * DD + ox];
      val = val >= 0.f ? val : 0.01f * val;
    }
    out_corr[t] = val;
    const int m = (1 << lvl) - 1;
    if (((y | x) & m) == 0) {
      const int S = 96 >> lvl;
      out_dw[((size_t)(b * 81 + d) * S + (y >> lvl)) * S + (x >> lvl)] = val;
      contrib = val;
    }
  }
#pragma unroll
  for (int off = 32; off; off >>= 1)
    contrib = fmaxf(contrib, __shfl_down(contrib, off));
  __shared__ float wm[4];
  if ((threadIdx.x & 63) == 0) wm[threadIdx.x >> 6] = contrib;
  __syncthreads();
  if (threadIdx.x == 0)
    maxbuf[blockIdx.x] =
        fmaxf(fmaxf(wm[0], wm[1]), fmaxf(wm[2], wm[3]));
}

// Reduce per-block maxima (5832 per level) into slots[lvl]. grid(6).
__global__ __launch_bounds__(1024) void k_finmax(
    const float* __restrict__ maxbuf, unsigned int* __restrict__ slots) {
  const int lvl = blockIdx.x;
  const float* mb = maxbuf + (size_t)lvl * 5832;
  float m = 0.f;
  for (int i = threadIdx.x; i < 5832; i += 1024) m = fmaxf(m, mb[i]);
#pragma unroll
  for (int off = 32; off; off >>= 1) m = fmaxf(m, __shfl_down(m, off));
  __shared__ float wm[16];
  if ((threadIdx.x & 63) == 0) wm[threadIdx.x >> 6] = m;
  __syncthreads();
  if (threadIdx.x == 0) {
    float r = wm[0];
#pragma unroll
    for (int i = 1; i < 16; ++i) r = fmaxf(r, wm[i]);
    slots[lvl] = (unsigned int)__float_as_int(r);
  }
}

// Normalize: out[dwoff+t] = out[srcoff+t] / max  (float32).
__global__ __launch_bounds__(256) void k_norm(
    float* __restrict__ out, const unsigned int* __restrict__ slots,
    const int lvl, const size_t dwoff, const size_t srcoff, const int n) {
  const int t = blockIdx.x * 256 + threadIdx.x;
  if (t >= n) return;
  const float m = __int_as_float((int)slots[lvl]);
  out[dwoff + t] = out[srcoff + t] / m;
}

// Last 6 dw0 elements alias the slot bytes: read slot0 first, then write.
__global__ __launch_bounds__(64) void k_norm0_tail(
    float* __restrict__ out, const unsigned int* __restrict__ slots) {
  const float m = __int_as_float((int)slots[0]);
  if (threadIdx.x < 6) {
    const int t = 1492986 + threadIdx.x;
    out[t] = out[1492992 + t] / m;
  }
}

extern "C" void kernel_launch(void* const* d_in, const int* in_sizes, int n_in,
                              void* d_out, int out_size, void* d_ws,
                              size_t ws_size, hipStream_t stream) {
  const float* x[6];
  const float* xp[6];
  for (int i = 0; i < 6; ++i) {
    x[i] = (const float*)d_in[2 * i];
    xp[i] = (const float*)d_in[2 * i + 1];
  }
  float* out = (float*)d_out;

  static const size_t dwoff[6] = {0,       2985984, 4852224,
                                  6438528, 7954848, 9453672};
  static const size_t croff[6] = {1492992, 3359232, 4945536,
                                  6461856, 7960680, 9455130};

  // Scratch inside dw0 element region [0, 1492992):
  float* lc1 = out;            // 115200
  float* lc2 = lc1 + 115200;   // 10368
  float* lc3 = lc2 + 10368;    // 2592
  float* lc4 = lc3 + 2592;     // 648
  float* lc5 = lc4 + 648;      // 162  (ends 128970)
  float* P2 = out + 200000;    // 82944
  float* P3 = out + 300000;    // 20736
  float* P4 = out + 330000;    // 5184
  float* P5 = out + 340000;    // 1296 (ends 341296)
  float* maxbuf = out + 400000;  // 6*5832 = 34992 (ends 434992)
  unsigned int* slots = (unsigned int*)(out + 1492986);
  // corr0 partials (5971968 floats) in level1..4 regions; consumed before
  // k_lc1p / k_expand reuse that space.
  float* part0 = out + 2985984;
  // part1 (921600 floats) in corr1 region, consumed before k_expand(1).
  float* part1 = out + croff[1];

  float* lcs[6] = {nullptr, lc1, lc2, lc3, lc4, lc5};
  float* Ps[6] = {nullptr, nullptr, P2, P3, P4, P5};
  const int Cs[6] = {512, 1024, 512, 256, 256, 256};

  k_corr0p<<<dim3(96, 4, 2), dim3(128), 0, stream>>>(x[0], xp[0], part0);
  k_corr0red<<<dim3(5832), dim3(256), 0, stream>>>(part0, out + croff[0],
                                                   maxbuf);
  k_lc1p<<<dim3(48, 8, 2), dim3(64), 0, stream>>>(x[1], xp[1], part1);
  k_red1<<<dim3((115200 + 255) / 256), dim3(256), 0, stream>>>(part1, lc1);
  for (int l = 2; l <= 5; ++l) {
    int S = 96 >> l;
    int RW = 64 / S;
    int cpg = Cs[l] / 8;
    k_lcrow<<<dim3((S + RW - 1) / RW, 8, 2), dim3(64), 0, stream>>>(
        x[l], xp[l], Ps[l], S, Cs[l], cpg, RW);
  }
  for (int l = 2; l <= 5; ++l) {
    int S = 96 >> l;
    int n = 2 * S * S * 9;
    k_lcred<<<dim3((n + 255) / 256), dim3(256), 0, stream>>>(Ps[l], lcs[l], S);
  }
  for (int l = 1; l <= 5; ++l) {
    int R = (l == 1) ? 2 : 1;
    k_expand<<<dim3(5832), dim3(256), 0, stream>>>(
        lcs[l], out + croff[l], out + dwoff[l], maxbuf + (size_t)l * 5832, l,
        R);
  }
  k_finmax<<<dim3(6), dim3(1024), 0, stream>>>(maxbuf, slots);
  for (int l = 1; l <= 5; ++l) {
    int S = 96 >> l;
    int n = 162 * S * S;
    k_norm<<<dim3((n + 255) / 256), dim3(256), 0, stream>>>(
        out, slots, l, dwoff[l], dwoff[l], n);
  }
  k_norm<<<dim3((1492986 + 255) / 256), dim3(256), 0, stream>>>(
      out, slots, 0, dwoff[0], croff[0], 1492986);
  k_norm0_tail<<<dim3(1), dim3(64), 0, stream>>>(out, slots);
}

// Round 10
// 227.982 us; speedup vs baseline: 13.4656x; 1.4463x over previous
//
#include <hip/hip_runtime.h>

#define CEIL(a, b) (((a) + (b) - 1) / (b))

// ---------------------------------------------------------------------------
// Corr_upsample_resize_norm: 6-level correlation pyramid.
// INPUT ORDER: x0, xp0, x1, xp1, ..., x5, xp5, motion_state (f32).
// OUTPUT: float32, out_size = 10,948,122: [dw0, corr0, dw1, corr1, ...].
// Scratch map (inside d_out, consumed before region finalized):
//   dw0 region [0, 1492992): lc1[115200]@0, lc2@115200, lc3@125568,
//     lc4@128160, lc5@128808; P2@200000, P3@300000, P4@330000, P5@340000;
//     maxbuf[6*5832]@400000; uint slots[6] @ elem 1492986.
//   part0[5971968] @ 2985984 (consumed by k_corr0red before lc1p/expand).
//   part1[3686400] @ 3359232 (consumed by k_red1 before expand_all).
// Launch order enforces all aliasing: corr0p -> corr0red -> lc1p -> red1 ->
// lcrow_all -> lcred_all -> expand_all -> finmax -> norm_all -> tail.
// ---------------------------------------------------------------------------

// Level 0 partials. Wave-per-row, channel-split G=4, dy-split 3.
// grid (96, 12, 2): blockIdx.y = gc*3 + dyg. block 128 (lane=x, 96 active).
// acc[j][dxi] on lane x: f1[y, x+4-dxi] * f2[y + dyg*3+j - 4, x].
// part layout: [g'=gc*3+dyg][b][y][j][dxi][x96].
__global__ __launch_bounds__(128) void k_corr0p(
    const float* __restrict__ f1, const float* __restrict__ f2,
    float* __restrict__ part) {
  const int x = threadIdx.x;   // active < 96
  const int y = blockIdx.x;    // 0..95
  const int gc = blockIdx.y / 3;
  const int dyg = blockIdx.y % 3;
  const int b = blockIdx.z;
  const bool xin = (x < 96);

  float acc[3][9];
#pragma unroll
  for (int j = 0; j < 3; ++j)
#pragma unroll
    for (int i = 0; i < 9; ++i) acc[j][i] = 0.f;

  bool okdx[9], okdy[3];
  int off1[9], off2[3];
#pragma unroll
  for (int i = 0; i < 9; ++i) {
    int xs = x + 4 - i;
    okdx[i] = xin && (xs >= 0) && (xs < 96);
    off1[i] = y * 96 + (xs < 0 ? 0 : (xs > 95 ? 95 : xs));
  }
#pragma unroll
  for (int j = 0; j < 3; ++j) {
    int yy = y + dyg * 3 + j - 4;
    okdy[j] = xin && (yy >= 0) && (yy < 96);
    off2[j] = (yy < 0 ? 0 : (yy > 95 ? 95 : yy)) * 96 + (xin ? x : 0);
  }

  const float* f1b = f1 + (size_t)b * 512 * 9216;
  const float* f2b = f2 + (size_t)b * 512 * 9216;
  const int c0 = gc * 128;
#pragma unroll 2
  for (int c = c0; c < c0 + 128; ++c) {
    const float* p = f1b + (size_t)c * 9216;
    const float* q = f2b + (size_t)c * 9216;
    float as[9], v[3];
#pragma unroll
    for (int i = 0; i < 9; ++i) as[i] = okdx[i] ? p[off1[i]] : 0.f;
#pragma unroll
    for (int j = 0; j < 3; ++j) v[j] = okdy[j] ? q[off2[j]] : 0.f;
#pragma unroll
    for (int j = 0; j < 3; ++j)
#pragma unroll
      for (int i = 0; i < 9; ++i) acc[j][i] = fmaf(as[i], v[j], acc[j][i]);
  }

  if (xin) {
    size_t base =
        ((size_t)(((gc * 3 + dyg) * 2 + b) * 96 + y)) * 2592 + x;
#pragma unroll
    for (int j = 0; j < 3; ++j)
#pragma unroll
      for (int i = 0; i < 9; ++i)
        part[base + (size_t)(j * 9 + i) * 96] = acc[j][i];
  }
}

// Reduce 4 channel groups, regroup x, leaky, store corr0, block max.
__global__ __launch_bounds__(256) void k_corr0red(
    const float* __restrict__ part, float* __restrict__ corr0,
    float* __restrict__ maxbuf) {
  const int t = blockIdx.x * 256 + threadIdx.x;  // < 1492992 exact
  const int x = t % 96;
  const int y = (t / 96) % 96;
  const int d = (t / 9216) % 81;
  const int b = t / 746496;
  const int dy = d / 9, dx = d % 9;
  const int dyg = dy / 3, j = dy % 3;
  const int xs = x + dx - 4;
  float v = 0.f;
  if (xs >= 0 && xs < 96) {
    size_t base =
        ((size_t)((dyg * 2 + b) * 96 + y)) * 2592 + (j * 9 + dx) * 96 + xs;
    v = part[base] + part[base + 1492992] + part[base + 2 * 1492992] +
        part[base + 3 * 1492992];
  }
  v = v >= 0.f ? v : 0.01f * v;
  corr0[t] = v;
  float mx = v;
#pragma unroll
  for (int off = 32; off; off >>= 1) mx = fmaxf(mx, __shfl_down(mx, off));
  __shared__ float wm[4];
  if ((threadIdx.x & 63) == 0) wm[threadIdx.x >> 6] = mx;
  __syncthreads();
  if (threadIdx.x == 0)
    maxbuf[blockIdx.x] = fmaxf(fmaxf(wm[0], wm[1]), fmaxf(wm[2], wm[3]));
}

// Level 1 partials, channel-split G=32. grid (48, 32, 2), block 64.
__global__ __launch_bounds__(64) void k_lc1p(
    const float* __restrict__ f1, const float* __restrict__ f2,
    float* __restrict__ part) {
  const int X = threadIdx.x;          // active < 48
  const int Y = blockIdx.x;           // 0..47
  const int gc = blockIdx.y;          // 0..31
  const int b = blockIdx.z;
  const bool xin = (X < 48);

  float acc2[5][5];
#pragma unroll
  for (int i = 0; i < 5; ++i)
#pragma unroll
    for (int j = 0; j < 5; ++j) acc2[i][j] = 0.f;

  bool okdy[5];
#pragma unroll
  for (int dy = 0; dy < 5; ++dy) {
    int YY = Y + dy - 2;
    okdy[dy] = (YY >= 0 && YY < 48);
  }
  const float* p1 = f1 + (size_t)b * 1024 * 2304 + Y * 48;
  const float* p2 = f2 + (size_t)b * 1024 * 2304;

  const int c0 = gc * 32;
#pragma unroll 2
  for (int c = c0; c < c0 + 32; ++c) {
    float a = xin ? p1[(size_t)c * 2304 + X] : 0.f;
    float as[5];
#pragma unroll
    for (int dx = 0; dx < 5; ++dx) {
      int src = X - dx + 2;
      src = src < 0 ? 0 : (src > 63 ? 63 : src);
      as[dx] = (dx == 2) ? a : __shfl(a, src);
    }
#pragma unroll
    for (int dy = 0; dy < 5; ++dy) {
      int YY = Y + dy - 2;
      float v = (okdy[dy] && xin) ? p2[(size_t)c * 2304 + YY * 48 + X] : 0.f;
#pragma unroll
      for (int dx = 0; dx < 5; ++dx)
        acc2[dy][dx] = fmaf(as[dx], v, acc2[dy][dx]);
    }
  }

  float* pb = part + ((size_t)(gc * 2 + b) * 25) * 2304 + Y * 48;
#pragma unroll
  for (int dy = 0; dy < 5; ++dy)
#pragma unroll
    for (int dx = 0; dx < 5; ++dx) {
      int src = X + dx - 2;
      int scl = src < 0 ? 0 : (src > 63 ? 63 : src);
      float val = __shfl(acc2[dy][dx], scl);
      bool okx = (X + dx - 2 >= 0) && (X + dx - 2 < 48);
      if (xin)
        pb[(size_t)(dy * 5 + dx) * 2304 + X] = (okdy[dy] && okx) ? val : 0.f;
    }
}

// Sum the 32 channel-group partials into lc1 ([b][Y][X][25] layout).
__global__ __launch_bounds__(256) void k_red1(const float* __restrict__ part,
                                              float* __restrict__ lc1) {
  const int t = blockIdx.x * 256 + threadIdx.x;
  if (t >= 115200) return;
  const int o = t / 4608;
  const int pix = t % 4608;
  const int b = pix / 2304, r = pix % 2304;
  float s = 0.f;
#pragma unroll
  for (int g = 0; g < 32; ++g)
    s += part[((size_t)(g * 2 + b) * 25 + o) * 2304 + r];
  lc1[(size_t)pix * 25 + o] = s;
}

// Levels 2..5 partials fused. grid (17, 8, 2), block 64.
__global__ __launch_bounds__(64) void k_lcrow_all(
    const float* __restrict__ x2, const float* __restrict__ q2,
    const float* __restrict__ x3, const float* __restrict__ q3,
    const float* __restrict__ x4, const float* __restrict__ q4,
    const float* __restrict__ x5, const float* __restrict__ q5,
    float* __restrict__ out) {
  int bx = blockIdx.x;
  int S, C, RW;
  const float *f1, *f2;
  float* part;
  if (bx < 12) {
    S = 24; C = 512; RW = 2; f1 = x2; f2 = q2; part = out + 200000;
  } else if (bx < 15) {
    bx -= 12; S = 12; C = 256; RW = 5; f1 = x3; f2 = q3; part = out + 300000;
  } else if (bx < 16) {
    bx -= 15; S = 6; C = 256; RW = 10; f1 = x4; f2 = q4; part = out + 330000;
  } else {
    bx -= 16; S = 3; C = 256; RW = 21; f1 = x5; f2 = q5; part = out + 340000;
  }
  const int cpg = C / 8;
  const int lane = threadIdx.x;
  const int SS = S * S;
  const int yr = lane / S;
  const int X = lane % S;
  const int y = bx * RW + yr;
  const int gc = blockIdx.y;
  const int b = blockIdx.z;
  const bool act = (yr < RW) && (y < S);

  float acc[3][3];
#pragma unroll
  for (int i = 0; i < 3; ++i)
#pragma unroll
    for (int j = 0; j < 3; ++j) acc[i][j] = 0.f;

  bool okdx[3], okdy[3];
  int off1[3], off2[3];
#pragma unroll
  for (int i = 0; i < 3; ++i) {
    int xs = X + 1 - i;
    okdx[i] = act && (xs >= 0) && (xs < S);
    off1[i] = (act ? y : 0) * S + (xs < 0 ? 0 : (xs >= S ? S - 1 : xs));
    int yy = y + i - 1;
    okdy[i] = act && (yy >= 0) && (yy < S);
    off2[i] = (yy < 0 ? 0 : (yy >= S ? S - 1 : yy)) * S + X;
  }

  const float* f1b = f1 + (size_t)b * C * SS;
  const float* f2b = f2 + (size_t)b * C * SS;
  const int c0 = gc * cpg;
  for (int c = c0; c < c0 + cpg; ++c) {
    const float* p = f1b + (size_t)c * SS;
    const float* q = f2b + (size_t)c * SS;
    float as[3], v[3];
#pragma unroll
    for (int i = 0; i < 3; ++i) as[i] = okdx[i] ? p[off1[i]] : 0.f;
#pragma unroll
    for (int i = 0; i < 3; ++i) v[i] = okdy[i] ? q[off2[i]] : 0.f;
#pragma unroll
    for (int dy = 0; dy < 3; ++dy)
#pragma unroll
      for (int dxi = 0; dxi < 3; ++dxi)
        acc[dy][dxi] = fmaf(as[dxi], v[dy], acc[dy][dxi]);
  }

  if (act) {
    size_t base = ((size_t)(gc * 2 + b) * S + y) * 9 * S + X;
#pragma unroll
    for (int dy = 0; dy < 3; ++dy)
#pragma unroll
      for (int dxi = 0; dxi < 3; ++dxi)
        part[base + (size_t)(dy * 3 + dxi) * S] = acc[dy][dxi];
  }
}

// Reduce G=8 + x-regroup into lc[p][9] for levels 2..5 (fused).
__global__ __launch_bounds__(256) void k_lcred_all(float* __restrict__ out) {
  int t = blockIdx.x * 256 + threadIdx.x;
  int S;
  const float* part;
  float* lc;
  if (t < 10368) {
    S = 24; part = out + 200000; lc = out + 115200;
  } else if ((t -= 10368) < 2592) {
    S = 12; part = out + 300000; lc = out + 125568;
  } else if ((t -= 2592) < 648) {
    S = 6; part = out + 330000; lc = out + 128160;
  } else if ((t -= 648) < 162) {
    S = 3; part = out + 340000; lc = out + 128808;
  } else {
    return;
  }
  const int SS = S * S;
  const int o = t % 9;
  const int p = t / 9;
  const int b = p / SS, r = p % SS, y = r / S, X = r % S;
  const int dy = o / 3, dx = o % 3;
  const int xs = X + dx - 1;
  float v = 0.f;
  if (xs >= 0 && xs < S) {
    size_t base = ((size_t)b * S + y) * 9 * S + (size_t)(dy * 3 + dx) * S + xs;
    const size_t gstride = (size_t)2 * S * 9 * S;
#pragma unroll
    for (int g = 0; g < 8; ++g) v += part[base + g * gstride];
  }
  lc[(size_t)p * 9 + o] = v;
}

// Expansion for levels 1..5 (fused): grid (5832, 5), blockIdx.y = lvl-1.
__global__ __launch_bounds__(256) void k_expand_all(
    float* __restrict__ out, float* __restrict__ maxbuf) {
  static const int lcoffs[6] = {0, 0, 115200, 125568, 128160, 128808};
  static const size_t dwo[6] = {0,       2985984, 4852224,
                                6438528, 7954848, 9453672};
  static const size_t cro[6] = {1492992, 3359232, 4945536,
                                6461856, 7960680, 9455130};
  const int lvl = (int)blockIdx.y + 1;
  const int R = (lvl == 1) ? 2 : 1;
  const float* lc = out + lcoffs[lvl];
  float* out_corr = out + cro[lvl];
  float* out_dw = out + dwo[lvl];
  const int t = blockIdx.x * 256 + threadIdx.x;
  float contrib = 0.f;
  {
    const int x = t % 96;
    const int y = (t / 96) % 96;
    const int d = (t / 9216) % 81;
    const int b = t / 746496;
    const int hy = y + d / 9 - 4;
    const int hx = x + d % 9 - 4;
    float val = 0.f;
    if (hy >= 0 && hy < 96 && hx >= 0 && hx < 96) {
      const int S = 96 >> lvl;
      const int Y1 = y >> lvl, X1 = x >> lvl;
      const int oy = (hy >> lvl) - Y1 + R;
      const int ox = (hx >> lvl) - X1 + R;
      const int DD = 2 * R + 1;
      val = lc[(((size_t)(b * S + Y1) * S + X1) * DD + oy) * DD + ox];
      val = val >= 0.f ? val : 0.01f * val;
    }
    out_corr[t] = val;
    const int m = (1 << lvl) - 1;
    if (((y | x) & m) == 0) {
      const int S = 96 >> lvl;
      out_dw[((size_t)(b * 81 + d) * S + (y >> lvl)) * S + (x >> lvl)] = val;
      contrib = val;
    }
  }
#pragma unroll
  for (int off = 32; off; off >>= 1)
    contrib = fmaxf(contrib, __shfl_down(contrib, off));
  __shared__ float wm[4];
  if ((threadIdx.x & 63) == 0) wm[threadIdx.x >> 6] = contrib;
  __syncthreads();
  if (threadIdx.x == 0)
    maxbuf[(size_t)lvl * 5832 + blockIdx.x] =
        fmaxf(fmaxf(wm[0], wm[1]), fmaxf(wm[2], wm[3]));
}

// Reduce per-block maxima (5832 per level) into slots[lvl]. grid(6).
__global__ __launch_bounds__(1024) void k_finmax(
    const float* __restrict__ maxbuf, unsigned int* __restrict__ slots) {
  const int lvl = blockIdx.x;
  const float* mb = maxbuf + (size_t)lvl * 5832;
  float m = 0.f;
  for (int i = threadIdx.x; i < 5832; i += 1024) m = fmaxf(m, mb[i]);
#pragma unroll
  for (int off = 32; off; off >>= 1) m = fmaxf(m, __shfl_down(m, off));
  __shared__ float wm[16];
  if ((threadIdx.x & 63) == 0) wm[threadIdx.x >> 6] = m;
  __syncthreads();
  if (threadIdx.x == 0) {
    float r = wm[0];
#pragma unroll
    for (int i = 1; i < 16; ++i) r = fmaxf(r, wm[i]);
    slots[lvl] = (unsigned int)__float_as_int(r);
  }
}

// All-level normalize (flat segmented, total 1,990,164 threads needed).
// Level 0: dw0 <- corr0/m0 (skips the 6 slot-aliased elements).
__global__ __launch_bounds__(256) void k_norm_all(
    float* __restrict__ out, const unsigned int* __restrict__ slots) {
  int i = blockIdx.x * 256 + threadIdx.x;
  int lvl;
  size_t dst, src;
  if (i < 1492986) {
    lvl = 0; dst = i; src = (size_t)1492992 + i;
  } else if ((i -= 1492986) < 373248) {
    lvl = 1; dst = (size_t)2985984 + i; src = dst;
  } else if ((i -= 373248) < 93312) {
    lvl = 2; dst = (size_t)4852224 + i; src = dst;
  } else if ((i -= 93312) < 23328) {
    lvl = 3; dst = (size_t)6438528 + i; src = dst;
  } else if ((i -= 23328) < 5832) {
    lvl = 4; dst = (size_t)7954848 + i; src = dst;
  } else if ((i -= 5832) < 1458) {
    lvl = 5; dst = (size_t)9453672 + i; src = dst;
  } else {
    return;
  }
  const float m = __int_as_float((int)slots[lvl]);
  out[dst] = out[src] / m;
}

// Last 6 dw0 elements alias the slot bytes: read slot0 first, then write.
__global__ __launch_bounds__(64) void k_norm0_tail(
    float* __restrict__ out, const unsigned int* __restrict__ slots) {
  const float m = __int_as_float((int)slots[0]);
  if (threadIdx.x < 6) {
    const int t = 1492986 + threadIdx.x;
    out[t] = out[1492992 + t] / m;
  }
}

extern "C" void kernel_launch(void* const* d_in, const int* in_sizes, int n_in,
                              void* d_out, int out_size, void* d_ws,
                              size_t ws_size, hipStream_t stream) {
  const float* x[6];
  const float* xp[6];
  for (int i = 0; i < 6; ++i) {
    x[i] = (const float*)d_in[2 * i];
    xp[i] = (const float*)d_in[2 * i + 1];
  }
  float* out = (float*)d_out;

  float* lc1 = out;                                      // 115200
  float* maxbuf = out + 400000;                          // 34992
  unsigned int* slots = (unsigned int*)(out + 1492986);  // 24 B
  float* part0 = out + 2985984;                          // 5971968
  float* part1 = out + 3359232;                          // 3686400

  const int NORM_TOTAL = 1492986 + 373248 + 93312 + 23328 + 5832 + 1458;

  k_corr0p<<<dim3(96, 12, 2), dim3(128), 0, stream>>>(x[0], xp[0], part0);
  k_corr0red<<<dim3(5832), dim3(256), 0, stream>>>(part0, out + 1492992,
                                                   maxbuf);
  k_lc1p<<<dim3(48, 32, 2), dim3(64), 0, stream>>>(x[1], xp[1], part1);
  k_red1<<<dim3(CEIL(115200, 256)), dim3(256), 0, stream>>>(part1, lc1);
  k_lcrow_all<<<dim3(17, 8, 2), dim3(64), 0, stream>>>(
      x[2], xp[2], x[3], xp[3], x[4], xp[4], x[5], xp[5], out);
  k_lcred_all<<<dim3(CEIL(13770, 256)), dim3(256), 0, stream>>>(out);
  k_expand_all<<<dim3(5832, 5), dim3(256), 0, stream>>>(out, maxbuf);
  k_finmax<<<dim3(6), dim3(1024), 0, stream>>>(maxbuf, slots);
  k_norm_all<<<dim3(CEIL(NORM_TOTAL, 256)), dim3(256), 0, stream>>>(out,
                                                                    slots);
  k_norm0_tail<<<dim3(1), dim3(64), 0, stream>>>(out, slots);
}

// Round 11
// 211.579 us; speedup vs baseline: 14.5096x; 1.0775x over previous
//
#include <hip/hip_runtime.h>

#define CEIL(a, b) (((a) + (b) - 1) / (b))

// ---------------------------------------------------------------------------
// Corr_upsample_resize_norm: 6-level correlation pyramid.
// INPUT ORDER: x0, xp0, x1, xp1, ..., x5, xp5, motion_state (f32).
// OUTPUT: float32, out_size = 10,948,122: [dw0, corr0, dw1, corr1, ...].
// Scratch map (inside d_out, consumed before region finalized):
//   dw0 region [0, 1492992): lc1[115200]@0, lc2@115200, lc3@125568,
//     lc4@128160, lc5@128808; P2@200000, P3@300000, P4@330000, P5@340000;
//     maxbuf[6*5832]@400000; uint slots[6] @ elem 1492986.
//   part0[5971968] @ 2985984 (consumed by k_corr0red BEFORE lc1p overwrites
//     the overlapping part1 range).
//   part1[3686400] @ 3359232 (consumed by k_red_all before expand_all).
// Order: corr0p -> corr0red -> lc1p -> lcrow_all -> red_all -> expand_all ->
//        finmax -> norm_all -> tail.
// ---------------------------------------------------------------------------

// Level 0 partials. Channel-split G=4, dy-split 3, 4 y-rows per block.
// grid (24, 12, 2): blockIdx.y = gc*3 + dyg. block 384 = 6 waves = 4 rows x
// 96 lanes EXACTLY (no idle lanes). No shuffles/syncs -> row-split across
// waves is safe. acc[j][dxi] on lane (yr,x): f1[y, x+4-dxi]*f2[y+dyg*3+j-4,x]
// part layout: [g'=gc*3+dyg][b][y][j][dxi][x96].
__global__ __launch_bounds__(384) void k_corr0p(
    const float* __restrict__ f1, const float* __restrict__ f2,
    float* __restrict__ part) {
  const int x = threadIdx.x % 96;
  const int yr = threadIdx.x / 96;  // 0..3
  const int y = blockIdx.x * 4 + yr;
  const int gc = blockIdx.y / 3;
  const int dyg = blockIdx.y % 3;
  const int b = blockIdx.z;

  float acc[3][9];
#pragma unroll
  for (int j = 0; j < 3; ++j)
#pragma unroll
    for (int i = 0; i < 9; ++i) acc[j][i] = 0.f;

  bool okdx[9], okdy[3];
  int off1[9], off2[3];
#pragma unroll
  for (int i = 0; i < 9; ++i) {
    int xs = x + 4 - i;
    okdx[i] = (xs >= 0) && (xs < 96);
    off1[i] = y * 96 + (xs < 0 ? 0 : (xs > 95 ? 95 : xs));
  }
#pragma unroll
  for (int j = 0; j < 3; ++j) {
    int yy = y + dyg * 3 + j - 4;
    okdy[j] = (yy >= 0) && (yy < 96);
    off2[j] = (yy < 0 ? 0 : (yy > 95 ? 95 : yy)) * 96 + x;
  }

  const float* f1b = f1 + (size_t)b * 512 * 9216;
  const float* f2b = f2 + (size_t)b * 512 * 9216;
  const int c0 = gc * 128;
#pragma unroll 2
  for (int c = c0; c < c0 + 128; ++c) {
    const float* p = f1b + (size_t)c * 9216;
    const float* q = f2b + (size_t)c * 9216;
    float as[9], v[3];
#pragma unroll
    for (int i = 0; i < 9; ++i) as[i] = okdx[i] ? p[off1[i]] : 0.f;
#pragma unroll
    for (int j = 0; j < 3; ++j) v[j] = okdy[j] ? q[off2[j]] : 0.f;
#pragma unroll
    for (int j = 0; j < 3; ++j)
#pragma unroll
      for (int i = 0; i < 9; ++i) acc[j][i] = fmaf(as[i], v[j], acc[j][i]);
  }

  size_t base = ((size_t)(((gc * 3 + dyg) * 2 + b) * 96 + y)) * 2592 + x;
#pragma unroll
  for (int j = 0; j < 3; ++j)
#pragma unroll
    for (int i = 0; i < 9; ++i)
      part[base + (size_t)(j * 9 + i) * 96] = acc[j][i];
}

// Reduce 4 channel groups, regroup x, leaky, store corr0, block max.
__global__ __launch_bounds__(256) void k_corr0red(
    const float* __restrict__ part, float* __restrict__ corr0,
    float* __restrict__ maxbuf) {
  const int t = blockIdx.x * 256 + threadIdx.x;  // < 1492992 exact
  const int x = t % 96;
  const int y = (t / 96) % 96;
  const int d = (t / 9216) % 81;
  const int b = t / 746496;
  const int dy = d / 9, dx = d % 9;
  const int dyg = dy / 3, j = dy % 3;
  const int xs = x + dx - 4;
  float v = 0.f;
  if (xs >= 0 && xs < 96) {
    size_t base =
        ((size_t)((dyg * 2 + b) * 96 + y)) * 2592 + (j * 9 + dx) * 96 + xs;
    v = part[base] + part[base + 1492992] + part[base + 2 * 1492992] +
        part[base + 3 * 1492992];
  }
  v = v >= 0.f ? v : 0.01f * v;
  corr0[t] = v;
  float mx = v;
#pragma unroll
  for (int off = 32; off; off >>= 1) mx = fmaxf(mx, __shfl_down(mx, off));
  __shared__ float wm[4];
  if ((threadIdx.x & 63) == 0) wm[threadIdx.x >> 6] = mx;
  __syncthreads();
  if (threadIdx.x == 0)
    maxbuf[blockIdx.x] = fmaxf(fmaxf(wm[0], wm[1]), fmaxf(wm[2], wm[3]));
}

// Level 1 partials, channel-split G=32. grid (48, 32, 2), block 64.
__global__ __launch_bounds__(64) void k_lc1p(
    const float* __restrict__ f1, const float* __restrict__ f2,
    float* __restrict__ part) {
  const int X = threadIdx.x;          // active < 48
  const int Y = blockIdx.x;           // 0..47
  const int gc = blockIdx.y;          // 0..31
  const int b = blockIdx.z;
  const bool xin = (X < 48);

  float acc2[5][5];
#pragma unroll
  for (int i = 0; i < 5; ++i)
#pragma unroll
    for (int j = 0; j < 5; ++j) acc2[i][j] = 0.f;

  bool okdy[5];
#pragma unroll
  for (int dy = 0; dy < 5; ++dy) {
    int YY = Y + dy - 2;
    okdy[dy] = (YY >= 0 && YY < 48);
  }
  const float* p1 = f1 + (size_t)b * 1024 * 2304 + Y * 48;
  const float* p2 = f2 + (size_t)b * 1024 * 2304;

  const int c0 = gc * 32;
#pragma unroll 2
  for (int c = c0; c < c0 + 32; ++c) {
    float a = xin ? p1[(size_t)c * 2304 + X] : 0.f;
    float as[5];
#pragma unroll
    for (int dx = 0; dx < 5; ++dx) {
      int src = X - dx + 2;
      src = src < 0 ? 0 : (src > 63 ? 63 : src);
      as[dx] = (dx == 2) ? a : __shfl(a, src);
    }
#pragma unroll
    for (int dy = 0; dy < 5; ++dy) {
      int YY = Y + dy - 2;
      float v = (okdy[dy] && xin) ? p2[(size_t)c * 2304 + YY * 48 + X] : 0.f;
#pragma unroll
      for (int dx = 0; dx < 5; ++dx)
        acc2[dy][dx] = fmaf(as[dx], v, acc2[dy][dx]);
    }
  }

  float* pb = part + ((size_t)(gc * 2 + b) * 25) * 2304 + Y * 48;
#pragma unroll
  for (int dy = 0; dy < 5; ++dy)
#pragma unroll
    for (int dx = 0; dx < 5; ++dx) {
      int src = X + dx - 2;
      int scl = src < 0 ? 0 : (src > 63 ? 63 : src);
      float val = __shfl(acc2[dy][dx], scl);
      bool okx = (X + dx - 2 >= 0) && (X + dx - 2 < 48);
      if (xin)
        pb[(size_t)(dy * 5 + dx) * 2304 + X] = (okdy[dy] && okx) ? val : 0.f;
    }
}

// Levels 2..5 partials fused. grid (17, 8, 2), block 64.
__global__ __launch_bounds__(64) void k_lcrow_all(
    const float* __restrict__ x2, const float* __restrict__ q2,
    const float* __restrict__ x3, const float* __restrict__ q3,
    const float* __restrict__ x4, const float* __restrict__ q4,
    const float* __restrict__ x5, const float* __restrict__ q5,
    float* __restrict__ out) {
  int bx = blockIdx.x;
  int S, C, RW;
  const float *f1, *f2;
  float* part;
  if (bx < 12) {
    S = 24; C = 512; RW = 2; f1 = x2; f2 = q2; part = out + 200000;
  } else if (bx < 15) {
    bx -= 12; S = 12; C = 256; RW = 5; f1 = x3; f2 = q3; part = out + 300000;
  } else if (bx < 16) {
    bx -= 15; S = 6; C = 256; RW = 10; f1 = x4; f2 = q4; part = out + 330000;
  } else {
    bx -= 16; S = 3; C = 256; RW = 21; f1 = x5; f2 = q5; part = out + 340000;
  }
  const int cpg = C / 8;
  const int lane = threadIdx.x;
  const int SS = S * S;
  const int yr = lane / S;
  const int X = lane % S;
  const int y = bx * RW + yr;
  const int gc = blockIdx.y;
  const int b = blockIdx.z;
  const bool act = (yr < RW) && (y < S);

  float acc[3][3];
#pragma unroll
  for (int i = 0; i < 3; ++i)
#pragma unroll
    for (int j = 0; j < 3; ++j) acc[i][j] = 0.f;

  bool okdx[3], okdy[3];
  int off1[3], off2[3];
#pragma unroll
  for (int i = 0; i < 3; ++i) {
    int xs = X + 1 - i;
    okdx[i] = act && (xs >= 0) && (xs < S);
    off1[i] = (act ? y : 0) * S + (xs < 0 ? 0 : (xs >= S ? S - 1 : xs));
    int yy = y + i - 1;
    okdy[i] = act && (yy >= 0) && (yy < S);
    off2[i] = (yy < 0 ? 0 : (yy >= S ? S - 1 : yy)) * S + X;
  }

  const float* f1b = f1 + (size_t)b * C * SS;
  const float* f2b = f2 + (size_t)b * C * SS;
  const int c0 = gc * cpg;
  for (int c = c0; c < c0 + cpg; ++c) {
    const float* p = f1b + (size_t)c * SS;
    const float* q = f2b + (size_t)c * SS;
    float as[3], v[3];
#pragma unroll
    for (int i = 0; i < 3; ++i) as[i] = okdx[i] ? p[off1[i]] : 0.f;
#pragma unroll
    for (int i = 0; i < 3; ++i) v[i] = okdy[i] ? q[off2[i]] : 0.f;
#pragma unroll
    for (int dy = 0; dy < 3; ++dy)
#pragma unroll
      for (int dxi = 0; dxi < 3; ++dxi)
        acc[dy][dxi] = fmaf(as[dxi], v[dy], acc[dy][dxi]);
  }

  if (act) {
    size_t base = ((size_t)(gc * 2 + b) * S + y) * 9 * S + X;
#pragma unroll
    for (int dy = 0; dy < 3; ++dy)
#pragma unroll
      for (int dxi = 0; dxi < 3; ++dxi)
        part[base + (size_t)(dy * 3 + dxi) * S] = acc[dy][dxi];
  }
}

// Fused reducer: level-1 (32 groups -> lc1) + levels 2..5 (8 groups -> lc).
// Flat index: [0,115200) = lc1; [115200, 128970) = lc2..lc5 segments.
__global__ __launch_bounds__(256) void k_red_all(float* __restrict__ out) {
  int t = blockIdx.x * 256 + threadIdx.x;
  if (t < 115200) {
    const float* part = out + 3359232;
    const int o = t / 4608;
    const int pix = t % 4608;
    const int b = pix / 2304, r = pix % 2304;
    float s = 0.f;
#pragma unroll
    for (int g = 0; g < 32; ++g)
      s += part[((size_t)(g * 2 + b) * 25 + o) * 2304 + r];
    out[(size_t)pix * 25 + o] = s;  // lc1 @ 0
    return;
  }
  t -= 115200;
  int S;
  const float* part;
  float* lc;
  if (t < 10368) {
    S = 24; part = out + 200000; lc = out + 115200;
  } else if ((t -= 10368) < 2592) {
    S = 12; part = out + 300000; lc = out + 125568;
  } else if ((t -= 2592) < 648) {
    S = 6; part = out + 330000; lc = out + 128160;
  } else if ((t -= 648) < 162) {
    S = 3; part = out + 340000; lc = out + 128808;
  } else {
    return;
  }
  const int SS = S * S;
  const int o = t % 9;
  const int p = t / 9;
  const int b = p / SS, r = p % SS, y = r / S, X = r % S;
  const int dy = o / 3, dx = o % 3;
  const int xs = X + dx - 1;
  float v = 0.f;
  if (xs >= 0 && xs < S) {
    size_t base = ((size_t)b * S + y) * 9 * S + (size_t)(dy * 3 + dx) * S + xs;
    const size_t gstride = (size_t)2 * S * 9 * S;
#pragma unroll
    for (int g = 0; g < 8; ++g) v += part[base + g * gstride];
  }
  lc[(size_t)p * 9 + o] = v;
}

// Expansion for levels 1..5 (fused): grid (5832, 5), blockIdx.y = lvl-1.
__global__ __launch_bounds__(256) void k_expand_all(
    float* __restrict__ out, float* __restrict__ maxbuf) {
  static const int lcoffs[6] = {0, 0, 115200, 125568, 128160, 128808};
  static const size_t dwo[6] = {0,       2985984, 4852224,
                                6438528, 7954848, 9453672};
  static const size_t cro[6] = {1492992, 3359232, 4945536,
                                6461856, 7960680, 9455130};
  const int lvl = (int)blockIdx.y + 1;
  const int R = (lvl == 1) ? 2 : 1;
  const float* lc = out + lcoffs[lvl];
  float* out_corr = out + cro[lvl];
  float* out_dw = out + dwo[lvl];
  const int t = blockIdx.x * 256 + threadIdx.x;
  float contrib = 0.f;
  {
    const int x = t % 96;
    const int y = (t / 96) % 96;
    const int d = (t / 9216) % 81;
    const int b = t / 746496;
    const int hy = y + d / 9 - 4;
    const int hx = x + d % 9 - 4;
    float val = 0.f;
    if (hy >= 0 && hy < 96 && hx >= 0 && hx < 96) {
      const int S = 96 >> lvl;
      const int Y1 = y >> lvl, X1 = x >> lvl;
      const int oy = (hy >> lvl) - Y1 + R;
      const int ox = (hx >> lvl) - X1 + R;
      const int DD = 2 * R + 1;
      val = lc[(((size_t)(b * S + Y1) * S + X1) * DD + oy) * DD + ox];
      val = val >= 0.f ? val : 0.01f * val;
    }
    out_corr[t] = val;
    const int m = (1 << lvl) - 1;
    if (((y | x) & m) == 0) {
      const int S = 96 >> lvl;
      out_dw[((size_t)(b * 81 + d) * S + (y >> lvl)) * S + (x >> lvl)] = val;
      contrib = val;
    }
  }
#pragma unroll
  for (int off = 32; off; off >>= 1)
    contrib = fmaxf(contrib, __shfl_down(contrib, off));
  __shared__ float wm[4];
  if ((threadIdx.x & 63) == 0) wm[threadIdx.x >> 6] = contrib;
  __syncthreads();
  if (threadIdx.x == 0)
    maxbuf[(size_t)lvl * 5832 + blockIdx.x] =
        fmaxf(fmaxf(wm[0], wm[1]), fmaxf(wm[2], wm[3]));
}

// Reduce per-block maxima (5832 per level) into slots[lvl]. grid(6).
__global__ __launch_bounds__(1024) void k_finmax(
    const float* __restrict__ maxbuf, unsigned int* __restrict__ slots) {
  const int lvl = blockIdx.x;
  const float* mb = maxbuf + (size_t)lvl * 5832;
  float m = 0.f;
  for (int i = threadIdx.x; i < 5832; i += 1024) m = fmaxf(m, mb[i]);
#pragma unroll
  for (int off = 32; off; off >>= 1) m = fmaxf(m, __shfl_down(m, off));
  __shared__ float wm[16];
  if ((threadIdx.x & 63) == 0) wm[threadIdx.x >> 6] = m;
  __syncthreads();
  if (threadIdx.x == 0) {
    float r = wm[0];
#pragma unroll
    for (int i = 1; i < 16; ++i) r = fmaxf(r, wm[i]);
    slots[lvl] = (unsigned int)__float_as_int(r);
  }
}

// All-level normalize (flat segmented, total 1,990,164 threads needed).
// Level 0: dw0 <- corr0/m0 (skips the 6 slot-aliased elements).
__global__ __launch_bounds__(256) void k_norm_all(
    float* __restrict__ out, const unsigned int* __restrict__ slots) {
  int i = blockIdx.x * 256 + threadIdx.x;
  int lvl;
  size_t dst, src;
  if (i < 1492986) {
    lvl = 0; dst = i; src = (size_t)1492992 + i;
  } else if ((i -= 1492986) < 373248) {
    lvl = 1; dst = (size_t)2985984 + i; src = dst;
  } else if ((i -= 373248) < 93312) {
    lvl = 2; dst = (size_t)4852224 + i; src = dst;
  } else if ((i -= 93312) < 23328) {
    lvl = 3; dst = (size_t)6438528 + i; src = dst;
  } else if ((i -= 23328) < 5832) {
    lvl = 4; dst = (size_t)7954848 + i; src = dst;
  } else if ((i -= 5832) < 1458) {
    lvl = 5; dst = (size_t)9453672 + i; src = dst;
  } else {
    return;
  }
  const float m = __int_as_float((int)slots[lvl]);
  out[dst] = out[src] / m;
}

// Last 6 dw0 elements alias the slot bytes: read slot0 first, then write.
__global__ __launch_bounds__(64) void k_norm0_tail(
    float* __restrict__ out, const unsigned int* __restrict__ slots) {
  const float m = __int_as_float((int)slots[0]);
  if (threadIdx.x < 6) {
    const int t = 1492986 + threadIdx.x;
    out[t] = out[1492992 + t] / m;
  }
}

extern "C" void kernel_launch(void* const* d_in, const int* in_sizes, int n_in,
                              void* d_out, int out_size, void* d_ws,
                              size_t ws_size, hipStream_t stream) {
  const float* x[6];
  const float* xp[6];
  for (int i = 0; i < 6; ++i) {
    x[i] = (const float*)d_in[2 * i];
    xp[i] = (const float*)d_in[2 * i + 1];
  }
  float* out = (float*)d_out;

  float* maxbuf = out + 400000;                          // 34992
  unsigned int* slots = (unsigned int*)(out + 1492986);  // 24 B
  float* part0 = out + 2985984;                          // 5971968
  float* part1 = out + 3359232;                          // 3686400

  const int NORM_TOTAL = 1492986 + 373248 + 93312 + 23328 + 5832 + 1458;

  k_corr0p<<<dim3(24, 12, 2), dim3(384), 0, stream>>>(x[0], xp[0], part0);
  k_corr0red<<<dim3(5832), dim3(256), 0, stream>>>(part0, out + 1492992,
                                                   maxbuf);
  k_lc1p<<<dim3(48, 32, 2), dim3(64), 0, stream>>>(x[1], xp[1], part1);
  k_lcrow_all<<<dim3(17, 8, 2), dim3(64), 0, stream>>>(
      x[2], xp[2], x[3], xp[3], x[4], xp[4], x[5], xp[5], out);
  k_red_all<<<dim3(CEIL(128970, 256)), dim3(256), 0, stream>>>(out);
  k_expand_all<<<dim3(5832, 5), dim3(256), 0, stream>>>(out, maxbuf);
  k_finmax<<<dim3(6), dim3(1024), 0, stream>>>(maxbuf, slots);
  k_norm_all<<<dim3(CEIL(NORM_TOTAL, 256)), dim3(256), 0, stream>>>(out,
                                                                    slots);
  k_norm0_tail<<<dim3(1), dim3(64), 0, stream>>>(out, slots);
}

// Round 12
// 190.657 us; speedup vs baseline: 16.1018x; 1.1097x over previous
//
#include <hip/hip_runtime.h>
#include <hip/hip_bf16.h>

#define CEIL(a, b) (((a) + (b) - 1) / (b))

typedef __hip_bfloat16 bf16;

// ---------------------------------------------------------------------------
// Corr_upsample_resize_norm: 6-level correlation pyramid.
// INPUT ORDER: x0, xp0, x1, xp1, ..., x5, xp5, motion_state (f32).
// OUTPUT: float32, out_size = 10,948,122: [dw0, corr0, dw1, corr1, ...].
// Scratch map (inside d_out, consumed before region finalized):
//   dw0 region [0, 1492992): lc1[115200]@0, lc2@115200, lc3@125568,
//     lc4@128160, lc5@128808; P2@200000, P3@300000, P4@330000, P5@340000;
//     maxbuf[6*5832]@400000; uint slots[6] @ elem 1492986.
//   part0: 11,943,936 BF16 values @ float-elem 2985984 (same 23.9 MB bytes;
//     consumed by k_corr0red BEFORE lc1p overwrites the overlapping bytes).
//   part1[3686400] f32 @ 3359232 (consumed by k_red_all before expand_all).
// Order: corr0p -> corr0red -> lc1p -> lcrow_all -> red_all -> expand_all ->
//        finmax -> norm_all -> tail.
// ---------------------------------------------------------------------------

// Level 0 partials. Channel-split G=8 (64 ch), dy-split 3, 4 y-rows/block.
// grid (24, 24, 2): blockIdx.y = gc*3 + dyg (= partial-group id g').
// block 384 = 6 waves = 4 rows x 96 lanes exactly. Partials stored BF16
// (|vals| ~30, bf16 rounding << absmax threshold).
// part layout: [g'][b][y][j*9+dxi][x96], bf16.
__global__ __launch_bounds__(384) void k_corr0p(
    const float* __restrict__ f1, const float* __restrict__ f2,
    bf16* __restrict__ part) {
  const int x = threadIdx.x % 96;
  const int yr = threadIdx.x / 96;  // 0..3
  const int y = blockIdx.x * 4 + yr;
  const int gp = blockIdx.y;        // g' = gc*3 + dyg
  const int gc = gp / 3;
  const int dyg = gp % 3;
  const int b = blockIdx.z;

  float acc[3][9];
#pragma unroll
  for (int j = 0; j < 3; ++j)
#pragma unroll
    for (int i = 0; i < 9; ++i) acc[j][i] = 0.f;

  bool okdx[9], okdy[3];
  int off1[9], off2[3];
#pragma unroll
  for (int i = 0; i < 9; ++i) {
    int xs = x + 4 - i;
    okdx[i] = (xs >= 0) && (xs < 96);
    off1[i] = y * 96 + (xs < 0 ? 0 : (xs > 95 ? 95 : xs));
  }
#pragma unroll
  for (int j = 0; j < 3; ++j) {
    int yy = y + dyg * 3 + j - 4;
    okdy[j] = (yy >= 0) && (yy < 96);
    off2[j] = (yy < 0 ? 0 : (yy > 95 ? 95 : yy)) * 96 + x;
  }

  const float* f1b = f1 + (size_t)b * 512 * 9216;
  const float* f2b = f2 + (size_t)b * 512 * 9216;
  const int c0 = gc * 64;
#pragma unroll 2
  for (int c = c0; c < c0 + 64; ++c) {
    const float* p = f1b + (size_t)c * 9216;
    const float* q = f2b + (size_t)c * 9216;
    float as[9], v[3];
#pragma unroll
    for (int i = 0; i < 9; ++i) as[i] = okdx[i] ? p[off1[i]] : 0.f;
#pragma unroll
    for (int j = 0; j < 3; ++j) v[j] = okdy[j] ? q[off2[j]] : 0.f;
#pragma unroll
    for (int j = 0; j < 3; ++j)
#pragma unroll
      for (int i = 0; i < 9; ++i) acc[j][i] = fmaf(as[i], v[j], acc[j][i]);
  }

  size_t base = ((size_t)((gp * 2 + b) * 96 + y)) * 2592 + x;
#pragma unroll
  for (int j = 0; j < 3; ++j)
#pragma unroll
    for (int i = 0; i < 9; ++i)
      part[base + (size_t)(j * 9 + i) * 96] = __float2bfloat16(acc[j][i]);
}

// Reduce 8 channel groups (bf16 partials), regroup x, leaky, store corr0,
// block max -> maxbuf.
__global__ __launch_bounds__(256) void k_corr0red(
    const bf16* __restrict__ part, float* __restrict__ corr0,
    float* __restrict__ maxbuf) {
  const int t = blockIdx.x * 256 + threadIdx.x;  // < 1492992 exact
  const int x = t % 96;
  const int y = (t / 96) % 96;
  const int d = (t / 9216) % 81;
  const int b = t / 746496;
  const int dy = d / 9, dx = d % 9;
  const int dyg = dy / 3, j = dy % 3;
  const int xs = x + dx - 4;
  float v = 0.f;
  if (xs >= 0 && xs < 96) {
    size_t base = ((size_t)((dyg * 2 + b) * 96 + y)) * 2592 +
                  (size_t)(j * 9 + dx) * 96 + xs;
    const size_t gstride = (size_t)6 * 96 * 2592;  // 3 dyg * 2 b * 96 * 2592
#pragma unroll
    for (int gc = 0; gc < 8; ++gc)
      v += __bfloat162float(part[base + gc * gstride]);
  }
  v = v >= 0.f ? v : 0.01f * v;
  corr0[t] = v;
  float mx = v;
#pragma unroll
  for (int off = 32; off; off >>= 1) mx = fmaxf(mx, __shfl_down(mx, off));
  __shared__ float wm[4];
  if ((threadIdx.x & 63) == 0) wm[threadIdx.x >> 6] = mx;
  __syncthreads();
  if (threadIdx.x == 0)
    maxbuf[blockIdx.x] = fmaxf(fmaxf(wm[0], wm[1]), fmaxf(wm[2], wm[3]));
}

// Level 1 partials, channel-split G=32. grid (48, 32, 2), block 64.
__global__ __launch_bounds__(64) void k_lc1p(
    const float* __restrict__ f1, const float* __restrict__ f2,
    float* __restrict__ part) {
  const int X = threadIdx.x;          // active < 48
  const int Y = blockIdx.x;           // 0..47
  const int gc = blockIdx.y;          // 0..31
  const int b = blockIdx.z;
  const bool xin = (X < 48);

  float acc2[5][5];
#pragma unroll
  for (int i = 0; i < 5; ++i)
#pragma unroll
    for (int j = 0; j < 5; ++j) acc2[i][j] = 0.f;

  bool okdy[5];
#pragma unroll
  for (int dy = 0; dy < 5; ++dy) {
    int YY = Y + dy - 2;
    okdy[dy] = (YY >= 0 && YY < 48);
  }
  const float* p1 = f1 + (size_t)b * 1024 * 2304 + Y * 48;
  const float* p2 = f2 + (size_t)b * 1024 * 2304;

  const int c0 = gc * 32;
#pragma unroll 2
  for (int c = c0; c < c0 + 32; ++c) {
    float a = xin ? p1[(size_t)c * 2304 + X] : 0.f;
    float as[5];
#pragma unroll
    for (int dx = 0; dx < 5; ++dx) {
      int src = X - dx + 2;
      src = src < 0 ? 0 : (src > 63 ? 63 : src);
      as[dx] = (dx == 2) ? a : __shfl(a, src);
    }
#pragma unroll
    for (int dy = 0; dy < 5; ++dy) {
      int YY = Y + dy - 2;
      float v = (okdy[dy] && xin) ? p2[(size_t)c * 2304 + YY * 48 + X] : 0.f;
#pragma unroll
      for (int dx = 0; dx < 5; ++dx)
        acc2[dy][dx] = fmaf(as[dx], v, acc2[dy][dx]);
    }
  }

  float* pb = part + ((size_t)(gc * 2 + b) * 25) * 2304 + Y * 48;
#pragma unroll
  for (int dy = 0; dy < 5; ++dy)
#pragma unroll
    for (int dx = 0; dx < 5; ++dx) {
      int src = X + dx - 2;
      int scl = src < 0 ? 0 : (src > 63 ? 63 : src);
      float val = __shfl(acc2[dy][dx], scl);
      bool okx = (X + dx - 2 >= 0) && (X + dx - 2 < 48);
      if (xin)
        pb[(size_t)(dy * 5 + dx) * 2304 + X] = (okdy[dy] && okx) ? val : 0.f;
    }
}

// Levels 2..5 partials fused. grid (17, 8, 2), block 64.
__global__ __launch_bounds__(64) void k_lcrow_all(
    const float* __restrict__ x2, const float* __restrict__ q2,
    const float* __restrict__ x3, const float* __restrict__ q3,
    const float* __restrict__ x4, const float* __restrict__ q4,
    const float* __restrict__ x5, const float* __restrict__ q5,
    float* __restrict__ out) {
  int bx = blockIdx.x;
  int S, C, RW;
  const float *f1, *f2;
  float* part;
  if (bx < 12) {
    S = 24; C = 512; RW = 2; f1 = x2; f2 = q2; part = out + 200000;
  } else if (bx < 15) {
    bx -= 12; S = 12; C = 256; RW = 5; f1 = x3; f2 = q3; part = out + 300000;
  } else if (bx < 16) {
    bx -= 15; S = 6; C = 256; RW = 10; f1 = x4; f2 = q4; part = out + 330000;
  } else {
    bx -= 16; S = 3; C = 256; RW = 21; f1 = x5; f2 = q5; part = out + 340000;
  }
  const int cpg = C / 8;
  const int lane = threadIdx.x;
  const int SS = S * S;
  const int yr = lane / S;
  const int X = lane % S;
  const int y = bx * RW + yr;
  const int gc = blockIdx.y;
  const int b = blockIdx.z;
  const bool act = (yr < RW) && (y < S);

  float acc[3][3];
#pragma unroll
  for (int i = 0; i < 3; ++i)
#pragma unroll
    for (int j = 0; j < 3; ++j) acc[i][j] = 0.f;

  bool okdx[3], okdy[3];
  int off1[3], off2[3];
#pragma unroll
  for (int i = 0; i < 3; ++i) {
    int xs = X + 1 - i;
    okdx[i] = act && (xs >= 0) && (xs < S);
    off1[i] = (act ? y : 0) * S + (xs < 0 ? 0 : (xs >= S ? S - 1 : xs));
    int yy = y + i - 1;
    okdy[i] = act && (yy >= 0) && (yy < S);
    off2[i] = (yy < 0 ? 0 : (yy >= S ? S - 1 : yy)) * S + X;
  }

  const float* f1b = f1 + (size_t)b * C * SS;
  const float* f2b = f2 + (size_t)b * C * SS;
  const int c0 = gc * cpg;
  for (int c = c0; c < c0 + cpg; ++c) {
    const float* p = f1b + (size_t)c * SS;
    const float* q = f2b + (size_t)c * SS;
    float as[3], v[3];
#pragma unroll
    for (int i = 0; i < 3; ++i) as[i] = okdx[i] ? p[off1[i]] : 0.f;
#pragma unroll
    for (int i = 0; i < 3; ++i) v[i] = okdy[i] ? q[off2[i]] : 0.f;
#pragma unroll
    for (int dy = 0; dy < 3; ++dy)
#pragma unroll
      for (int dxi = 0; dxi < 3; ++dxi)
        acc[dy][dxi] = fmaf(as[dxi], v[dy], acc[dy][dxi]);
  }

  if (act) {
    size_t base = ((size_t)(gc * 2 + b) * S + y) * 9 * S + X;
#pragma unroll
    for (int dy = 0; dy < 3; ++dy)
#pragma unroll
      for (int dxi = 0; dxi < 3; ++dxi)
        part[base + (size_t)(dy * 3 + dxi) * S] = acc[dy][dxi];
  }
}

// Fused reducer: level-1 (32 groups -> lc1) + levels 2..5 (8 groups -> lc).
__global__ __launch_bounds__(256) void k_red_all(float* __restrict__ out) {
  int t = blockIdx.x * 256 + threadIdx.x;
  if (t < 115200) {
    const float* part = out + 3359232;
    const int o = t / 4608;
    const int pix = t % 4608;
    const int b = pix / 2304, r = pix % 2304;
    float s = 0.f;
#pragma unroll
    for (int g = 0; g < 32; ++g)
      s += part[((size_t)(g * 2 + b) * 25 + o) * 2304 + r];
    out[(size_t)pix * 25 + o] = s;  // lc1 @ 0
    return;
  }
  t -= 115200;
  int S;
  const float* part;
  float* lc;
  if (t < 10368) {
    S = 24; part = out + 200000; lc = out + 115200;
  } else if ((t -= 10368) < 2592) {
    S = 12; part = out + 300000; lc = out + 125568;
  } else if ((t -= 2592) < 648) {
    S = 6; part = out + 330000; lc = out + 128160;
  } else if ((t -= 648) < 162) {
    S = 3; part = out + 340000; lc = out + 128808;
  } else {
    return;
  }
  const int SS = S * S;
  const int o = t % 9;
  const int p = t / 9;
  const int b = p / SS, r = p % SS, y = r / S, X = r % S;
  const int dy = o / 3, dx = o % 3;
  const int xs = X + dx - 1;
  float v = 0.f;
  if (xs >= 0 && xs < S) {
    size_t base = ((size_t)b * S + y) * 9 * S + (size_t)(dy * 3 + dx) * S + xs;
    const size_t gstride = (size_t)2 * S * 9 * S;
#pragma unroll
    for (int g = 0; g < 8; ++g) v += part[base + g * gstride];
  }
  lc[(size_t)p * 9 + o] = v;
}

// Expansion for levels 1..5 (fused): grid (5832, 5), blockIdx.y = lvl-1.
__global__ __launch_bounds__(256) void k_expand_all(
    float* __restrict__ out, float* __restrict__ maxbuf) {
  static const int lcoffs[6] = {0, 0, 115200, 125568, 128160, 128808};
  static const size_t dwo[6] = {0,       2985984, 4852224,
                                6438528, 7954848, 9453672};
  static const size_t cro[6] = {1492992, 3359232, 4945536,
                                6461856, 7960680, 9455130};
  const int lvl = (int)blockIdx.y + 1;
  const int R = (lvl == 1) ? 2 : 1;
  const float* lc = out + lcoffs[lvl];
  float* out_corr = out + cro[lvl];
  float* out_dw = out + dwo[lvl];
  const int t = blockIdx.x * 256 + threadIdx.x;
  float contrib = 0.f;
  {
    const int x = t % 96;
    const int y = (t / 96) % 96;
    const int d = (t / 9216) % 81;
    const int b = t / 746496;
    const int hy = y + d / 9 - 4;
    const int hx = x + d % 9 - 4;
    float val = 0.f;
    if (hy >= 0 && hy < 96 && hx >= 0 && hx < 96) {
      const int S = 96 >> lvl;
      const int Y1 = y >> lvl, X1 = x >> lvl;
      const int oy = (hy >> lvl) - Y1 + R;
      const int ox = (hx >> lvl) - X1 + R;
      const int DD = 2 * R + 1;
      val = lc[(((size_t)(b * S + Y1) * S + X1) * DD + oy) * DD + ox];
      val = val >= 0.f ? val : 0.01f * val;
    }
    out_corr[t] = val;
    const int m = (1 << lvl) - 1;
    if (((y | x) & m) == 0) {
      const int S = 96 >> lvl;
      out_dw[((size_t)(b * 81 + d) * S + (y >> lvl)) * S + (x >> lvl)] = val;
      contrib = val;
    }
  }
#pragma unroll
  for (int off = 32; off; off >>= 1)
    contrib = fmaxf(contrib, __shfl_down(contrib, off));
  __shared__ float wm[4];
  if ((threadIdx.x & 63) == 0) wm[threadIdx.x >> 6] = contrib;
  __syncthreads();
  if (threadIdx.x == 0)
    maxbuf[(size_t)lvl * 5832 + blockIdx.x] =
        fmaxf(fmaxf(wm[0], wm[1]), fmaxf(wm[2], wm[3]));
}

// Reduce per-block maxima (5832 per level) into slots[lvl]. grid(6).
__global__ __launch_bounds__(1024) void k_finmax(
    const float* __restrict__ maxbuf, unsigned int* __restrict__ slots) {
  const int lvl = blockIdx.x;
  const float* mb = maxbuf + (size_t)lvl * 5832;
  float m = 0.f;
  for (int i = threadIdx.x; i < 5832; i += 1024) m = fmaxf(m, mb[i]);
#pragma unroll
  for (int off = 32; off; off >>= 1) m = fmaxf(m, __shfl_down(m, off));
  __shared__ float wm[16];
  if ((threadIdx.x & 63) == 0) wm[threadIdx.x >> 6] = m;
  __syncthreads();
  if (threadIdx.x == 0) {
    float r = wm[0];
#pragma unroll
    for (int i = 1; i < 16; ++i) r = fmaxf(r, wm[i]);
    slots[lvl] = (unsigned int)__float_as_int(r);
  }
}

// All-level normalize (flat segmented, total 1,990,164 threads needed).
__global__ __launch_bounds__(256) void k_norm_all(
    float* __restrict__ out, const unsigned int* __restrict__ slots) {
  int i = blockIdx.x * 256 + threadIdx.x;
  int lvl;
  size_t dst, src;
  if (i < 1492986) {
    lvl = 0; dst = i; src = (size_t)1492992 + i;
  } else if ((i -= 1492986) < 373248) {
    lvl = 1; dst = (size_t)2985984 + i; src = dst;
  } else if ((i -= 373248) < 93312) {
    lvl = 2; dst = (size_t)4852224 + i; src = dst;
  } else if ((i -= 93312) < 23328) {
    lvl = 3; dst = (size_t)6438528 + i; src = dst;
  } else if ((i -= 23328) < 5832) {
    lvl = 4; dst = (size_t)7954848 + i; src = dst;
  } else if ((i -= 5832) < 1458) {
    lvl = 5; dst = (size_t)9453672 + i; src = dst;
  } else {
    return;
  }
  const float m = __int_as_float((int)slots[lvl]);
  out[dst] = out[src] / m;
}

// Last 6 dw0 elements alias the slot bytes: read slot0 first, then write.
__global__ __launch_bounds__(64) void k_norm0_tail(
    float* __restrict__ out, const unsigned int* __restrict__ slots) {
  const float m = __int_as_float((int)slots[0]);
  if (threadIdx.x < 6) {
    const int t = 1492986 + threadIdx.x;
    out[t] = out[1492992 + t] / m;
  }
}

extern "C" void kernel_launch(void* const* d_in, const int* in_sizes, int n_in,
                              void* d_out, int out_size, void* d_ws,
                              size_t ws_size, hipStream_t stream) {
  const float* x[6];
  const float* xp[6];
  for (int i = 0; i < 6; ++i) {
    x[i] = (const float*)d_in[2 * i];
    xp[i] = (const float*)d_in[2 * i + 1];
  }
  float* out = (float*)d_out;

  float* maxbuf = out + 400000;                          // 34992
  unsigned int* slots = (unsigned int*)(out + 1492986);  // 24 B
  bf16* part0 = (bf16*)(out + 2985984);                  // 11,943,936 bf16
  float* part1 = out + 3359232;                          // 3686400 f32

  const int NORM_TOTAL = 1492986 + 373248 + 93312 + 23328 + 5832 + 1458;

  k_corr0p<<<dim3(24, 24, 2), dim3(384), 0, stream>>>(x[0], xp[0], part0);
  k_corr0red<<<dim3(5832), dim3(256), 0, stream>>>(part0, out + 1492992,
                                                   maxbuf);
  k_lc1p<<<dim3(48, 32, 2), dim3(64), 0, stream>>>(x[1], xp[1], part1);
  k_lcrow_all<<<dim3(17, 8, 2), dim3(64), 0, stream>>>(
      x[2], xp[2], x[3], xp[3], x[4], xp[4], x[5], xp[5], out);
  k_red_all<<<dim3(CEIL(128970, 256)), dim3(256), 0, stream>>>(out);
  k_expand_all<<<dim3(5832, 5), dim3(256), 0, stream>>>(out, maxbuf);
  k_finmax<<<dim3(6), dim3(1024), 0, stream>>>(maxbuf, slots);
  k_norm_all<<<dim3(CEIL(NORM_TOTAL, 256)), dim3(256), 0, stream>>>(out,
                                                                    slots);
  k_norm0_tail<<<dim3(1), dim3(64), 0, stream>>>(out, slots);
}